// Round 12
// baseline (340.852 us; speedup 1.0000x reference)
//
#include <hip/hip_runtime.h>
#include <hip/hip_bf16.h>
#include <stdint.h>

// Shapes (fixed by the problem)
#define B_  16
#define M_  2048            // T*N
#define C_  256
#define BM_ 32768           // B_*M_

typedef __bf16 bf16x8 __attribute__((ext_vector_type(8)));
typedef __bf16 bf16x2 __attribute__((ext_vector_type(2)));
typedef float  f32x4  __attribute__((ext_vector_type(4)));
typedef float  f32x16 __attribute__((ext_vector_type(16)));
typedef unsigned int uint2v __attribute__((ext_vector_type(2)));

__device__ __forceinline__ unsigned short f2bf(float f) {
    uint32_t u = __builtin_bit_cast(uint32_t, f);
    u += 0x7fffu + ((u >> 16) & 1u);          // RNE
    return (unsigned short)(u >> 16);
}

__device__ __forceinline__ uint32_t pkbf(float a, float b) {
    bf16x2 t; t[0] = (__bf16)a; t[1] = (__bf16)b;   // compiler -> v_cvt_pk_bf16_f32
    return __builtin_bit_cast(uint32_t, t);
}

__device__ __forceinline__ float bf2f(unsigned short u) {
    return __builtin_bit_cast(float, ((uint32_t)u) << 16);
}

// async global->LDS, 16B/lane; LDS dest = wave-uniform base, HW adds lane*16
__device__ __forceinline__ void gload16(const void* g, void* l) {
    __builtin_amdgcn_global_load_lds(
        (const __attribute__((address_space(1))) void*)g,
        (__attribute__((address_space(3))) void*)l, 16, 0, 0);
}

// Explicit LDS-DMA publish: drain vmcnt BEFORE the barrier, fence scheduler.
__device__ __forceinline__ void publish_barrier() {
    asm volatile("s_waitcnt vmcnt(0)" ::: "memory");
    __builtin_amdgcn_sched_barrier(0);
    __syncthreads();
    __builtin_amdgcn_sched_barrier(0);
}

// ---------------------------------------------------------------- kernel 1
// adjT5 = 5*log2(e) * adj^T (logits in exp2 domain); affwB = bf16(affine_w)
__global__ void prep_weights(const float* __restrict__ adj,
                             const float* __restrict__ affw,
                             unsigned short* __restrict__ adjT5,
                             unsigned short* __restrict__ affwB) {
    int idx = blockIdx.x * 256 + threadIdx.x;   // 0..65535
    int d = idx >> 8, c = idx & 255;
    adjT5[d * 256 + c] = f2bf(7.2134752f * adj[c * 256 + d]);
    affwB[idx] = f2bf(affw[idx]);
}

// ---------------------------------------------------------------- kernel 2
__global__ void l2norm_kernel(const float* __restrict__ x,
                              unsigned short* __restrict__ nf,
                              float* __restrict__ norms) {
    int w = threadIdx.x >> 6, lane = threadIdx.x & 63;
    int row = blockIdx.x * 4 + w;
    const float4 v = *reinterpret_cast<const float4*>(x + (size_t)row * 256 + lane * 4);
    float ss = v.x * v.x + v.y * v.y + v.z * v.z + v.w * v.w;
    #pragma unroll
    for (int m = 1; m < 64; m <<= 1) ss += __shfl_xor(ss, m);
    float nrm = sqrtf(ss);
    float s = 1.0f / fmaxf(nrm, 1e-12f);
    ushort4 o;
    o.x = f2bf(v.x * s); o.y = f2bf(v.y * s); o.z = f2bf(v.z * s); o.w = f2bf(v.w * s);
    *reinterpret_cast<ushort4*>(nf + (size_t)row * 256 + lane * 4) = o;
    if (lane == 0) norms[row] = nrm;
}

// ---------------------------------------------------------------- kernel 3
// One pass over nf producing Q (row-major), V3 (flash-staging-linear),
// K3 (flash-staging-linear) — as r9.
__global__ __launch_bounds__(512, 2)
void dual_gemm(const unsigned short* __restrict__ A,
               const unsigned short* __restrict__ B1,
               const unsigned short* __restrict__ B2,
               const float* __restrict__ norms,
               const float* __restrict__ bias,
               unsigned short* __restrict__ outQ,
               unsigned short* __restrict__ outV3,
               unsigned short* __restrict__ outK3) {
    __shared__ unsigned short bb1[256 * 56];
    __shared__ unsigned short bb2[256 * 56];
    int tid = threadIdx.x;
    int w = tid >> 6, lane = tid & 63, g = lane >> 4, r = lane & 15;
    int m0 = blockIdx.x * 128;

    const f32x4 z = {0.f, 0.f, 0.f, 0.f};
    f32x4 accq[16], accv[16];
    #pragma unroll
    for (int i = 0; i < 16; i++) { accq[i] = z; accv[i] = z; }

    int row = m0 + w * 16 + r;
    int kvblk_r = row >> 5, mrow = row & 31;

    for (int dc = 0; dc < 8; dc++) {
        __syncthreads();
        #pragma unroll
        for (int it = 0; it < 2; it++) {
            int n = (w * 2 + it) * 16 + (lane >> 2);
            int t = lane & 3;
            *reinterpret_cast<uint4*>(&bb1[n * 56 + t * 8]) =
                *reinterpret_cast<const uint4*>(B1 + (size_t)n * 256 + dc * 32 + t * 8);
            *reinterpret_cast<uint4*>(&bb2[n * 56 + t * 8]) =
                *reinterpret_cast<const uint4*>(B2 + (size_t)n * 256 + dc * 32 + t * 8);
        }
        __syncthreads();
        bf16x8 af = *reinterpret_cast<const bf16x8*>(
            A + (size_t)row * 256 + dc * 32 + g * 8);
        // K3 store: c-range = dc*32+g*8 -> ch = dc*2+(g>>1), khl = g&1
        {
            int ch = dc * 2 + (g >> 1);
            int khl = g & 1;
            *reinterpret_cast<bf16x8*>(
                outK3 + (size_t)kvblk_r * 8192 + ch * 512 + (khl * 32 + mrow) * 8) = af;
        }
        #pragma unroll
        for (int nf16 = 0; nf16 < 16; nf16++) {
            bf16x8 b1f = *reinterpret_cast<const bf16x8*>(&bb1[(nf16 * 16 + r) * 56 + g * 8]);
            accq[nf16] = __builtin_amdgcn_mfma_f32_16x16x32_bf16(af, b1f, accq[nf16], 0, 0, 0);
            bf16x8 b2f = *reinterpret_cast<const bf16x8*>(&bb2[(nf16 * 16 + r) * 56 + g * 8]);
            accv[nf16] = __builtin_amdgcn_mfma_f32_16x16x32_bf16(af, b2f, accv[nf16], 0, 0, 0);
        }
    }
    // Q epilogue: row-major
    #pragma unroll
    for (int nf16 = 0; nf16 < 16; nf16++) {
        int n = nf16 * 16 + r;
        #pragma unroll
        for (int j = 0; j < 4; j++) {
            int m = m0 + w * 16 + g * 4 + j;
            outQ[(size_t)m * 256 + n] = f2bf(accq[nf16][j]);
        }
    }
    // V3 epilogue: staging-linear layout, * norms + bias
    int mm = m0 + w * 16 + g * 4;               // kv row of acc elem 0 (4-aligned)
    int kvblk = mm >> 5;
    int kv0 = mm & 31;
    int jj  = kv0 >> 4;                         // 16-kv half
    int hl2 = (kv0 >> 3) & 1;                   // 8-kv sub
    int e0  = kv0 & 7;                          // 0 or 4
    float4 nr = *reinterpret_cast<const float4*>(norms + mm);
    #pragma unroll
    for (int nf16 = 0; nf16 < 16; nf16++) {
        int n = nf16 * 16 + r;
        int cb = n >> 5, mr2 = n & 31;
        int slot = (cb * 2 + jj) * 64 + hl2 * 32 + mr2;
        float bv = bias[n];
        ushort4 o;
        o.x = f2bf(accv[nf16][0] * nr.x + bv);
        o.y = f2bf(accv[nf16][1] * nr.y + bv);
        o.z = f2bf(accv[nf16][2] * nr.z + bv);
        o.w = f2bf(accv[nf16][3] * nr.w + bv);
        *reinterpret_cast<ushort4*>(outV3 + (size_t)kvblk * 8192 + slot * 8 + e0) = o;
    }
}

// ---------------------------------------------------------------- kernel 4
// Flash v13 = r11 fixed-max structure + OPTIONAL fused last-block merge.
// fused=1: both kv-half blocks write bf16 partials + weight, threadfence,
// atomicAdd per-tile flag; the SECOND block re-reads both partials (same-XCD
// L2) and does merge + LN + LeakyReLU. No spin, dispatch-order-safe,
// deterministic (merger reads both partials from memory).
// fused=0: r11 behavior (h=0 -> f32 out, h=1 -> part1; merge kernel after).
// LDS 64KB: K0@0 K1@16K V0@32K V1@48K -> 2 independent blocks/CU.
__global__ __launch_bounds__(256, 2)
void flash_kernel(const unsigned short* __restrict__ Q,
                  const unsigned short* __restrict__ K3,
                  const unsigned short* __restrict__ V3,
                  float* __restrict__ out,
                  unsigned short* __restrict__ part0,
                  unsigned short* __restrict__ part1,
                  float* __restrict__ ml,
                  int* __restrict__ flags,
                  const float* __restrict__ gam,
                  const float* __restrict__ bet,
                  int fused) {
    __shared__ __align__(16) char smem[65536];
    __shared__ int lastFlag;
    const int tid = threadIdx.x;
    const int w = tid >> 6, lane = tid & 63;
    const int hl = lane >> 5, m = lane & 31;    // lane half, lane-in-half
    const int blk = blockIdx.x;
    const int idx = blk >> 3;                   // 0..63
    const int b = (blk & 7) * 2 + (idx >> 5);   // XCD-pinned batch
    const int sub = idx & 31;
    const int mblk = sub >> 1, h = sub & 1;     // q-tile, kv half
    const int q0 = b * M_ + mblk * 128 + w * 32;

    // Q fragments: B-operand; lane holds Q[q0+m][ch*16 + hl*8 ..+8]
    bf16x8 qf[16];
    #pragma unroll
    for (int ch = 0; ch < 16; ch++)
        qf[ch] = *reinterpret_cast<const bf16x8*>(
            Q + (size_t)(q0 + m) * 256 + ch * 16 + hl * 8);

    const f32x16 z16 = {0,0,0,0, 0,0,0,0, 0,0,0,0, 0,0,0,0};
    f32x16 acc[8];
    #pragma unroll
    for (int cb = 0; cb < 8; cb++) acc[cb] = z16;
    float lsum = 0.0f;                          // exp2 domain, fixed max = 0

    // staging sources: fully linear; per-thread base, +8192 ushorts/step
    const unsigned short* Ksrc =
        K3 + ((size_t)(b * 64 + h * 32) * 1024 + tid) * 8;
    const unsigned short* Vsrc =
        V3 + ((size_t)(b * 64 + h * 32) * 1024 + tid) * 8;

    auto stageK = [&](int step, int buf) {
        char* kb = smem + buf * 16384;
        const unsigned short* src = Ksrc + (size_t)step * 8192;
        #pragma unroll
        for (int it = 0; it < 4; it++)
            gload16(src + it * 2048, kb + (it * 256 + w * 64) * 16);
    };
    auto stageV = [&](int step, int buf) {
        char* vb = smem + 32768 + buf * 16384;
        const unsigned short* src = Vsrc + (size_t)step * 8192;
        #pragma unroll
        for (int it = 0; it < 4; it++)
            gload16(src + it * 2048, vb + (it * 256 + w * 64) * 16);
    };

    stageK(0, 0); stageV(0, 0);
    publish_barrier();
    stageK(1, 1); stageV(1, 1);

    for (int step = 0; step < 32; step++) {
        const int cur = step & 1;
        const char* kbl = smem + cur * 16384 + lane * 16;
        const char* vbl = smem + 32768 + cur * 16384 + lane * 16;

        // ---- S^T[32 kv][32 q] = K . Q^T  (linear conflict-free kf reads)
        f32x16 sf = z16;
        __builtin_amdgcn_s_setprio(1);
        #pragma unroll
        for (int ch = 0; ch < 16; ch++) {
            bf16x8 kf = *reinterpret_cast<const bf16x8*>(kbl + ch * 1024);
            sf = __builtin_amdgcn_mfma_f32_32x32x16_bf16(kf, qf[ch], sf, 0, 0, 0);
        }
        __builtin_amdgcn_s_setprio(0);

        // ---- fixed-max softmax: P = exp2(sf)
        #pragma unroll
        for (int i = 0; i < 16; i++) {
            sf[i] = exp2f(sf[i]);
            lsum += sf[i];
        }
        // pack P; lane holds P[q=m][kv=(reg&3)+8*(reg>>2)+4*hl]
        uint32_t pk0 = pkbf(sf[0], sf[1]),   pk1 = pkbf(sf[2], sf[3]);
        uint32_t pk2 = pkbf(sf[4], sf[5]),   pk3 = pkbf(sf[6], sf[7]);
        uint32_t pk4 = pkbf(sf[8], sf[9]),   pk5 = pkbf(sf[10], sf[11]);
        uint32_t pk6 = pkbf(sf[12], sf[13]), pk7 = pkbf(sf[14], sf[15]);
        uint2v r0 = __builtin_amdgcn_permlane32_swap(pk0, pk2, false, false);
        uint2v r1 = __builtin_amdgcn_permlane32_swap(pk1, pk3, false, false);
        uint2v r2 = __builtin_amdgcn_permlane32_swap(pk4, pk6, false, false);
        uint2v r3 = __builtin_amdgcn_permlane32_swap(pk5, pk7, false, false);
        uint4 u0; u0.x = r0[0]; u0.y = r1[0]; u0.z = r0[1]; u0.w = r1[1];
        uint4 u1; u1.x = r2[0]; u1.y = r3[0]; u1.z = r2[1]; u1.w = r3[1];
        bf16x8 pf0 = __builtin_bit_cast(bf16x8, u0);   // P^T[kv 0..15][q]
        bf16x8 pf1 = __builtin_bit_cast(bf16x8, u1);   // P^T[kv 16..31][q]

        // ---- out^T[c][q] += V . P^T  (linear, conflict-free V reads)
        __builtin_amdgcn_s_setprio(1);
        #pragma unroll
        for (int cb = 0; cb < 8; cb++) {
            bf16x8 v0 = *reinterpret_cast<const bf16x8*>(vbl + (cb * 2 + 0) * 1024);
            acc[cb] = __builtin_amdgcn_mfma_f32_32x32x16_bf16(v0, pf0, acc[cb], 0, 0, 0);
            bf16x8 v1 = *reinterpret_cast<const bf16x8*>(vbl + (cb * 2 + 1) * 1024);
            acc[cb] = __builtin_amdgcn_mfma_f32_32x32x16_bf16(v1, pf1, acc[cb], 0, 0, 0);
        }
        __builtin_amdgcn_s_setprio(0);

        // publish stage(step+1); all K/V reads of buf[cur] complete block-wide
        publish_barrier();
        if (step + 2 < 32) {                    // refill just-consumed buffers
            stageK(step + 2, cur);
            stageV(step + 2, cur);
        }
    }

    // ---- epilogue: per-q-row lsum, write normalized partial + weight
    lsum += __shfl_xor(lsum, 32);
    float inv = 1.0f / lsum;
    float wgt = lsum;                           // fixed max: weight = raw sum
    size_t qrow = (size_t)(q0 + m);

    if (fused) {
        unsigned short* myp = h ? part1 : part0;
        #pragma unroll
        for (int cb = 0; cb < 8; cb++)
            #pragma unroll
            for (int q4 = 0; q4 < 4; q4++) {
                int c0i = cb * 32 + q4 * 8 + 4 * hl;
                uint2 u;
                u.x = pkbf(acc[cb][q4 * 4 + 0] * inv, acc[cb][q4 * 4 + 1] * inv);
                u.y = pkbf(acc[cb][q4 * 4 + 2] * inv, acc[cb][q4 * 4 + 3] * inv);
                *reinterpret_cast<uint2*>(myp + qrow * 256 + c0i) = u;
            }
        if (hl == 0) ml[h * BM_ + qrow] = wgt;
        __threadfence();                        // release partials + weights
        if (tid == 0)
            lastFlag = (atomicAdd(&flags[b * 16 + mblk], 1) == 1);
        __syncthreads();
        if (lastFlag) {
            __threadfence();                    // acquire other block's data
            float w0 = ml[qrow], w1 = ml[BM_ + qrow];
            float rs = 1.0f / (w0 + w1);
            float a0 = w0 * rs, a1 = w1 * rs;
            const unsigned short* p0 = part0 + qrow * 256 + hl * 128;
            const unsigned short* p1 = part1 + qrow * 256 + hl * 128;
            // pass 1: stats over this lane's 128 channels
            float s = 0.0f, ssq = 0.0f;
            #pragma unroll 4
            for (int k = 0; k < 16; k++) {
                uint4 u0 = *reinterpret_cast<const uint4*>(p0 + k * 8);
                uint4 u1 = *reinterpret_cast<const uint4*>(p1 + k * 8);
                const uint32_t* a = &u0.x;
                const uint32_t* c = &u1.x;
                #pragma unroll
                for (int j = 0; j < 4; j++) {
                    float v0 = a0 * bf2f((unsigned short)(a[j] & 0xffff))
                             + a1 * bf2f((unsigned short)(c[j] & 0xffff));
                    float v1 = a0 * bf2f((unsigned short)(a[j] >> 16))
                             + a1 * bf2f((unsigned short)(c[j] >> 16));
                    s += v0 + v1; ssq += v0 * v0 + v1 * v1;
                }
            }
            s   += __shfl_xor(s, 32);
            ssq += __shfl_xor(ssq, 32);
            float mu = s * (1.0f / 256.0f);
            float var = ssq * (1.0f / 256.0f) - mu * mu;
            float rstd = rsqrtf(var + 1e-5f);
            // pass 2: recompute, LN + LeakyReLU, write
            #pragma unroll 4
            for (int k = 0; k < 16; k++) {
                uint4 u0 = *reinterpret_cast<const uint4*>(p0 + k * 8);
                uint4 u1 = *reinterpret_cast<const uint4*>(p1 + k * 8);
                const uint32_t* a = &u0.x;
                const uint32_t* c = &u1.x;
                int c0i = hl * 128 + k * 8;
                float4 g0 = *reinterpret_cast<const float4*>(gam + c0i);
                float4 g1 = *reinterpret_cast<const float4*>(gam + c0i + 4);
                float4 b0 = *reinterpret_cast<const float4*>(bet + c0i);
                float4 b1 = *reinterpret_cast<const float4*>(bet + c0i + 4);
                float vv[8];
                #pragma unroll
                for (int j = 0; j < 4; j++) {
                    vv[2 * j]     = a0 * bf2f((unsigned short)(a[j] & 0xffff))
                                  + a1 * bf2f((unsigned short)(c[j] & 0xffff));
                    vv[2 * j + 1] = a0 * bf2f((unsigned short)(a[j] >> 16))
                                  + a1 * bf2f((unsigned short)(c[j] >> 16));
                }
                float4 o0, o1;
                o0.x = (vv[0] - mu) * rstd * g0.x + b0.x;
                o0.y = (vv[1] - mu) * rstd * g0.y + b0.y;
                o0.z = (vv[2] - mu) * rstd * g0.z + b0.z;
                o0.w = (vv[3] - mu) * rstd * g0.w + b0.w;
                o1.x = (vv[4] - mu) * rstd * g1.x + b1.x;
                o1.y = (vv[5] - mu) * rstd * g1.y + b1.y;
                o1.z = (vv[6] - mu) * rstd * g1.z + b1.z;
                o1.w = (vv[7] - mu) * rstd * g1.w + b1.w;
                o0.x = o0.x >= 0.f ? o0.x : 0.01f * o0.x;
                o0.y = o0.y >= 0.f ? o0.y : 0.01f * o0.y;
                o0.z = o0.z >= 0.f ? o0.z : 0.01f * o0.z;
                o0.w = o0.w >= 0.f ? o0.w : 0.01f * o0.w;
                o1.x = o1.x >= 0.f ? o1.x : 0.01f * o1.x;
                o1.y = o1.y >= 0.f ? o1.y : 0.01f * o1.y;
                o1.z = o1.z >= 0.f ? o1.z : 0.01f * o1.z;
                o1.w = o1.w >= 0.f ? o1.w : 0.01f * o1.w;
                *reinterpret_cast<float4*>(out + qrow * 256 + c0i) = o0;
                *reinterpret_cast<float4*>(out + qrow * 256 + c0i + 4) = o1;
            }
        }
    } else {
        if (h == 0) {
            #pragma unroll
            for (int cb = 0; cb < 8; cb++)
                #pragma unroll
                for (int q4 = 0; q4 < 4; q4++) {
                    int c0i = cb * 32 + q4 * 8 + 4 * hl;
                    float4 o;
                    o.x = acc[cb][q4 * 4 + 0] * inv;
                    o.y = acc[cb][q4 * 4 + 1] * inv;
                    o.z = acc[cb][q4 * 4 + 2] * inv;
                    o.w = acc[cb][q4 * 4 + 3] * inv;
                    *reinterpret_cast<float4*>(out + qrow * 256 + c0i) = o;
                }
            if (hl == 0) ml[qrow] = wgt;
        } else {
            #pragma unroll
            for (int cb = 0; cb < 8; cb++)
                #pragma unroll
                for (int q4 = 0; q4 < 4; q4++) {
                    int c0i = cb * 32 + q4 * 8 + 4 * hl;
                    uint2 u;
                    u.x = pkbf(acc[cb][q4 * 4 + 0] * inv, acc[cb][q4 * 4 + 1] * inv);
                    u.y = pkbf(acc[cb][q4 * 4 + 2] * inv, acc[cb][q4 * 4 + 3] * inv);
                    *reinterpret_cast<uint2*>(part1 + qrow * 256 + c0i) = u;
                }
            if (hl == 0) ml[BM_ + qrow] = wgt;
        }
    }
}

// ---------------------------------------------------------------- kernel 5
// Fallback merge (only launched when ws too small for fused path).
__global__ void merge_ln_kernel(const unsigned short* __restrict__ part1,
                                const float* __restrict__ ml,
                                const float* __restrict__ gam,
                                const float* __restrict__ bet,
                                float* __restrict__ out) {
    int w = threadIdx.x >> 6, lane = threadIdx.x & 63;
    size_t row = (size_t)blockIdx.x * 4 + w;
    float w0 = ml[row], w1 = ml[BM_ + row];
    float rs = 1.0f / (w0 + w1);
    float4 o0 = *reinterpret_cast<float4*>(out + row * 256 + lane * 4);
    ushort4 p = *reinterpret_cast<const ushort4*>(part1 + row * 256 + lane * 4);
    float4 v;
    v.x = (w0 * o0.x + w1 * bf2f(p.x)) * rs;
    v.y = (w0 * o0.y + w1 * bf2f(p.y)) * rs;
    v.z = (w0 * o0.z + w1 * bf2f(p.z)) * rs;
    v.w = (w0 * o0.w + w1 * bf2f(p.w)) * rs;
    float s = v.x + v.y + v.z + v.w;
    float q = v.x * v.x + v.y * v.y + v.z * v.z + v.w * v.w;
    #pragma unroll
    for (int m = 1; m < 64; m <<= 1) { s += __shfl_xor(s, m); q += __shfl_xor(q, m); }
    float mu = s * (1.0f / 256.0f);
    float var = q * (1.0f / 256.0f) - mu * mu;
    float rstd = rsqrtf(var + 1e-5f);
    float4 gg = *reinterpret_cast<const float4*>(gam + lane * 4);
    float4 bb = *reinterpret_cast<const float4*>(bet + lane * 4);
    float4 o;
    o.x = (v.x - mu) * rstd * gg.x + bb.x;
    o.y = (v.y - mu) * rstd * gg.y + bb.y;
    o.z = (v.z - mu) * rstd * gg.z + bb.z;
    o.w = (v.w - mu) * rstd * gg.w + bb.w;
    o.x = o.x >= 0.f ? o.x : 0.01f * o.x;
    o.y = o.y >= 0.f ? o.y : 0.01f * o.y;
    o.z = o.z >= 0.f ? o.z : 0.01f * o.z;
    o.w = o.w >= 0.f ? o.w : 0.01f * o.w;
    *reinterpret_cast<float4*>(out + row * 256 + lane * 4) = o;
}

// ---------------------------------------------------------------- launcher
extern "C" void kernel_launch(void* const* d_in, const int* in_sizes, int n_in,
                              void* d_out, int out_size, void* d_ws, size_t ws_size,
                              hipStream_t stream) {
    const float* local_feat = (const float*)d_in[0];
    const float* adj_w    = (const float*)d_in[3];
    const float* affine_w = (const float*)d_in[4];
    const float* affine_b = (const float*)d_in[5];
    const float* ln_g     = (const float*)d_in[6];
    const float* ln_b     = (const float*)d_in[7];
    float* out = (float*)d_out;

    char* ws = (char*)d_ws;
    unsigned short* nf    = (unsigned short*)(ws);                 // 16 MiB (dead after dual_gemm)
    unsigned short* q     = (unsigned short*)(ws + 16777216);      // 16 MiB
    unsigned short* v3    = (unsigned short*)(ws + 33554432);      // 16 MiB
    float*          norms = (float*)         (ws + 50331648);      // 128 KiB
    unsigned short* adjT5 = (unsigned short*)(ws + 50462720);      // 128 KiB (dead after dual_gemm)
    unsigned short* affw  = (unsigned short*)(ws + 50593792);      // 128 KiB (dead after dual_gemm)
    unsigned short* k3    = (unsigned short*)(ws + 50724864);      // 16 MiB -> ends 67502080
    unsigned short* part0 = (unsigned short*)(ws);                 // aliases nf (dead)
    float*          ml    = (float*)         (ws + 50462720);      // aliases adjT5+affw (dead)

    // Fused last-block merge needs part1 + flags beyond 67502080.
    const size_t need = 67502080ull + 16777216ull + 4096ull;
    int fused = (ws_size >= need) ? 1 : 0;
    unsigned short* part1 = fused ? (unsigned short*)(ws + 67502080)
                                  : (unsigned short*)(ws);          // fallback aliases nf
    int* flags = (int*)(ws + 67502080 + 16777216);

    prep_weights<<<256, 256, 0, stream>>>(adj_w, affine_w, adjT5, affw);
    l2norm_kernel<<<BM_ / 4, 256, 0, stream>>>(local_feat, nf, norms);
    dual_gemm<<<BM_ / 128, 512, 0, stream>>>(nf, adjT5, affw, norms, affine_b, q, v3, k3);
    if (fused) hipMemsetAsync(flags, 0, 256 * sizeof(int), stream);
    flash_kernel<<<512, 256, 0, stream>>>(q, k3, v3, out, part0, part1, ml, flags,
                                          ln_g, ln_b, fused);
    if (!fused)
        merge_ln_kernel<<<BM_ / 4, 256, 0, stream>>>(part1, ml, ln_g, ln_b, out);
}

// Round 13
// 176.022 us; speedup vs baseline: 1.9364x; 1.9364x over previous
//
#include <hip/hip_runtime.h>
#include <hip/hip_bf16.h>
#include <stdint.h>

// Shapes (fixed by the problem)
#define B_  16
#define M_  2048            // T*N
#define C_  256
#define BM_ 32768           // B_*M_

typedef __bf16 bf16x8 __attribute__((ext_vector_type(8)));
typedef __bf16 bf16x2 __attribute__((ext_vector_type(2)));
typedef float  f32x4  __attribute__((ext_vector_type(4)));
typedef float  f32x16 __attribute__((ext_vector_type(16)));
typedef unsigned int uint2v __attribute__((ext_vector_type(2)));

__device__ __forceinline__ unsigned short f2bf(float f) {
    uint32_t u = __builtin_bit_cast(uint32_t, f);
    u += 0x7fffu + ((u >> 16) & 1u);          // RNE
    return (unsigned short)(u >> 16);
}

__device__ __forceinline__ uint32_t pkbf(float a, float b) {
    bf16x2 t; t[0] = (__bf16)a; t[1] = (__bf16)b;   // compiler -> v_cvt_pk_bf16_f32
    return __builtin_bit_cast(uint32_t, t);
}

__device__ __forceinline__ float bf2f(unsigned short u) {
    return __builtin_bit_cast(float, ((uint32_t)u) << 16);
}

// async global->LDS, 16B/lane; LDS dest = wave-uniform base, HW adds lane*16
__device__ __forceinline__ void gload16(const void* g, void* l) {
    __builtin_amdgcn_global_load_lds(
        (const __attribute__((address_space(1))) void*)g,
        (__attribute__((address_space(3))) void*)l, 16, 0, 0);
}

// Explicit LDS-DMA publish: drain vmcnt BEFORE the barrier, fence scheduler.
__device__ __forceinline__ void publish_barrier() {
    asm volatile("s_waitcnt vmcnt(0)" ::: "memory");
    __builtin_amdgcn_sched_barrier(0);
    __syncthreads();
    __builtin_amdgcn_sched_barrier(0);
}

// ---------------------------------------------------------------- kernel 1
// adjT5 = 5*log2(e) * adj^T (logits in exp2 domain); affwB = bf16(affine_w)
__global__ void prep_weights(const float* __restrict__ adj,
                             const float* __restrict__ affw,
                             unsigned short* __restrict__ adjT5,
                             unsigned short* __restrict__ affwB) {
    int idx = blockIdx.x * 256 + threadIdx.x;   // 0..65535
    int d = idx >> 8, c = idx & 255;
    adjT5[d * 256 + c] = f2bf(7.2134752f * adj[c * 256 + d]);
    affwB[idx] = f2bf(affw[idx]);
}

// ---------------------------------------------------------------- kernel 2
// FUSED l2norm + dual GEMM: reads local_feat f32, computes row norms
// in-register, converts to bf16 af fragments, then Q = af@adjT5 (row-major),
// V3 = norm*(af@affw)+bias (flash-staging-linear), K3 = af (staging-linear).
// launch_bounds(512,1): 128 AGPR acc + ~110 VGPR fits 256 (old (512,2)
// forced a 128-reg cap against 128 AGPRs -> permanent spill).
__global__ __launch_bounds__(512, 1)
void fused_gemm(const float* __restrict__ X,
                const unsigned short* __restrict__ B1,
                const unsigned short* __restrict__ B2,
                const float* __restrict__ bias,
                unsigned short* __restrict__ outQ,
                unsigned short* __restrict__ outV3,
                unsigned short* __restrict__ outK3) {
    __shared__ unsigned short bb1[256 * 56];
    __shared__ unsigned short bb2[256 * 56];
    int tid = threadIdx.x;
    int w = tid >> 6, lane = tid & 63, g = lane >> 4, r = lane & 15;
    int m0 = blockIdx.x * 128;
    int row = m0 + w * 16 + r;
    int kvblk_r = row >> 5, mrow = row & 31;

    // ---- load own 64 f32 of row, accumulate sum of squares
    float4 xv[16];
    float ss = 0.0f;
    #pragma unroll
    for (int dc = 0; dc < 8; dc++) {
        xv[2 * dc]     = *reinterpret_cast<const float4*>(
            X + (size_t)row * 256 + dc * 32 + g * 8);
        xv[2 * dc + 1] = *reinterpret_cast<const float4*>(
            X + (size_t)row * 256 + dc * 32 + g * 8 + 4);
        ss += xv[2 * dc].x     * xv[2 * dc].x     + xv[2 * dc].y     * xv[2 * dc].y
            + xv[2 * dc].z     * xv[2 * dc].z     + xv[2 * dc].w     * xv[2 * dc].w
            + xv[2 * dc + 1].x * xv[2 * dc + 1].x + xv[2 * dc + 1].y * xv[2 * dc + 1].y
            + xv[2 * dc + 1].z * xv[2 * dc + 1].z + xv[2 * dc + 1].w * xv[2 * dc + 1].w;
    }
    ss += __shfl_xor(ss, 16);
    ss += __shfl_xor(ss, 32);
    float nrm = sqrtf(ss);
    float scale = 1.0f / fmaxf(nrm, 1e-12f);
    // norms of rows w*16 + g*4 + j (for the V3 epilogue) via shuffle
    float4 nr;
    nr.x = __shfl(nrm, g * 4 + 0);
    nr.y = __shfl(nrm, g * 4 + 1);
    nr.z = __shfl(nrm, g * 4 + 2);
    nr.w = __shfl(nrm, g * 4 + 3);

    // ---- convert to bf16 fragments; store K3 (staging-linear)
    bf16x8 af[8];
    #pragma unroll
    for (int dc = 0; dc < 8; dc++) {
        uint4 u;
        u.x = pkbf(xv[2 * dc].x * scale,     xv[2 * dc].y * scale);
        u.y = pkbf(xv[2 * dc].z * scale,     xv[2 * dc].w * scale);
        u.z = pkbf(xv[2 * dc + 1].x * scale, xv[2 * dc + 1].y * scale);
        u.w = pkbf(xv[2 * dc + 1].z * scale, xv[2 * dc + 1].w * scale);
        af[dc] = __builtin_bit_cast(bf16x8, u);
        int ch = dc * 2 + (g >> 1);
        int khl = g & 1;
        *reinterpret_cast<bf16x8*>(
            outK3 + (size_t)kvblk_r * 8192 + ch * 512 + (khl * 32 + mrow) * 8) = af[dc];
    }

    const f32x4 z = {0.f, 0.f, 0.f, 0.f};
    f32x4 accq[16], accv[16];
    #pragma unroll
    for (int i = 0; i < 16; i++) { accq[i] = z; accv[i] = z; }

    for (int dc = 0; dc < 8; dc++) {
        __syncthreads();
        #pragma unroll
        for (int it = 0; it < 2; it++) {
            int n = (w * 2 + it) * 16 + (lane >> 2);
            int t = lane & 3;
            *reinterpret_cast<uint4*>(&bb1[n * 56 + t * 8]) =
                *reinterpret_cast<const uint4*>(B1 + (size_t)n * 256 + dc * 32 + t * 8);
            *reinterpret_cast<uint4*>(&bb2[n * 56 + t * 8]) =
                *reinterpret_cast<const uint4*>(B2 + (size_t)n * 256 + dc * 32 + t * 8);
        }
        __syncthreads();
        #pragma unroll
        for (int nf16 = 0; nf16 < 16; nf16++) {
            bf16x8 b1f = *reinterpret_cast<const bf16x8*>(&bb1[(nf16 * 16 + r) * 56 + g * 8]);
            accq[nf16] = __builtin_amdgcn_mfma_f32_16x16x32_bf16(af[dc], b1f, accq[nf16], 0, 0, 0);
            bf16x8 b2f = *reinterpret_cast<const bf16x8*>(&bb2[(nf16 * 16 + r) * 56 + g * 8]);
            accv[nf16] = __builtin_amdgcn_mfma_f32_16x16x32_bf16(af[dc], b2f, accv[nf16], 0, 0, 0);
        }
    }
    // Q epilogue: row-major
    #pragma unroll
    for (int nf16 = 0; nf16 < 16; nf16++) {
        int n = nf16 * 16 + r;
        #pragma unroll
        for (int j = 0; j < 4; j++) {
            int m = m0 + w * 16 + g * 4 + j;
            outQ[(size_t)m * 256 + n] = f2bf(accq[nf16][j]);
        }
    }
    // V3 epilogue: staging-linear layout, * norms + bias
    int mm = m0 + w * 16 + g * 4;
    int kvblk = mm >> 5;
    int kv0 = mm & 31;
    int jj  = kv0 >> 4;
    int hl2 = (kv0 >> 3) & 1;
    int e0  = kv0 & 7;
    #pragma unroll
    for (int nf16 = 0; nf16 < 16; nf16++) {
        int n = nf16 * 16 + r;
        int cb = n >> 5, mr2 = n & 31;
        int slot = (cb * 2 + jj) * 64 + hl2 * 32 + mr2;
        float bv = bias[n];
        ushort4 o;
        o.x = f2bf(accv[nf16][0] * nr.x + bv);
        o.y = f2bf(accv[nf16][1] * nr.y + bv);
        o.z = f2bf(accv[nf16][2] * nr.z + bv);
        o.w = f2bf(accv[nf16][3] * nr.w + bv);
        *reinterpret_cast<ushort4*>(outV3 + (size_t)kvblk * 8192 + slot * 8 + e0) = o;
    }
}

// ---------------------------------------------------------------- kernel 3
// Flash v14 = r11 body verbatim; epilogue writes bf16 partials for BOTH
// halves when h0bf16 (r12 proved both-halves-bf16 accuracy), else r11 mode.
// LDS 64KB: K0@0 K1@16K V0@32K V1@48K -> 2 independent blocks/CU.
__global__ __launch_bounds__(256, 2)
void flash_kernel(const unsigned short* __restrict__ Q,
                  const unsigned short* __restrict__ K3,
                  const unsigned short* __restrict__ V3,
                  float* __restrict__ out,
                  unsigned short* __restrict__ part0,
                  unsigned short* __restrict__ part1,
                  float* __restrict__ ml,
                  int h0bf16) {
    __shared__ __align__(16) char smem[65536];
    const int tid = threadIdx.x;
    const int w = tid >> 6, lane = tid & 63;
    const int hl = lane >> 5, m = lane & 31;    // lane half, lane-in-half
    const int blk = blockIdx.x;
    const int idx = blk >> 3;                   // 0..63
    const int b = (blk & 7) * 2 + (idx >> 5);   // XCD-pinned batch
    const int sub = idx & 31;
    const int mblk = sub >> 1, h = sub & 1;     // q-tile, kv half
    const int q0 = b * M_ + mblk * 128 + w * 32;

    // Q fragments: B-operand; lane holds Q[q0+m][ch*16 + hl*8 ..+8]
    bf16x8 qf[16];
    #pragma unroll
    for (int ch = 0; ch < 16; ch++)
        qf[ch] = *reinterpret_cast<const bf16x8*>(
            Q + (size_t)(q0 + m) * 256 + ch * 16 + hl * 8);

    const f32x16 z16 = {0,0,0,0, 0,0,0,0, 0,0,0,0, 0,0,0,0};
    f32x16 acc[8];
    #pragma unroll
    for (int cb = 0; cb < 8; cb++) acc[cb] = z16;
    float lsum = 0.0f;                          // exp2 domain, fixed max = 0

    // staging sources: fully linear; per-thread base, +8192 ushorts/step
    const unsigned short* Ksrc =
        K3 + ((size_t)(b * 64 + h * 32) * 1024 + tid) * 8;
    const unsigned short* Vsrc =
        V3 + ((size_t)(b * 64 + h * 32) * 1024 + tid) * 8;

    auto stageK = [&](int step, int buf) {
        char* kb = smem + buf * 16384;
        const unsigned short* src = Ksrc + (size_t)step * 8192;
        #pragma unroll
        for (int it = 0; it < 4; it++)
            gload16(src + it * 2048, kb + (it * 256 + w * 64) * 16);
    };
    auto stageV = [&](int step, int buf) {
        char* vb = smem + 32768 + buf * 16384;
        const unsigned short* src = Vsrc + (size_t)step * 8192;
        #pragma unroll
        for (int it = 0; it < 4; it++)
            gload16(src + it * 2048, vb + (it * 256 + w * 64) * 16);
    };

    stageK(0, 0); stageV(0, 0);
    publish_barrier();
    stageK(1, 1); stageV(1, 1);

    for (int step = 0; step < 32; step++) {
        const int cur = step & 1;
        const char* kbl = smem + cur * 16384 + lane * 16;
        const char* vbl = smem + 32768 + cur * 16384 + lane * 16;

        // ---- S^T[32 kv][32 q] = K . Q^T  (linear conflict-free kf reads)
        f32x16 sf = z16;
        __builtin_amdgcn_s_setprio(1);
        #pragma unroll
        for (int ch = 0; ch < 16; ch++) {
            bf16x8 kf = *reinterpret_cast<const bf16x8*>(kbl + ch * 1024);
            sf = __builtin_amdgcn_mfma_f32_32x32x16_bf16(kf, qf[ch], sf, 0, 0, 0);
        }
        __builtin_amdgcn_s_setprio(0);

        // ---- fixed-max softmax: P = exp2(sf)
        #pragma unroll
        for (int i = 0; i < 16; i++) {
            sf[i] = exp2f(sf[i]);
            lsum += sf[i];
        }
        // pack P; lane holds P[q=m][kv=(reg&3)+8*(reg>>2)+4*hl]
        uint32_t pk0 = pkbf(sf[0], sf[1]),   pk1 = pkbf(sf[2], sf[3]);
        uint32_t pk2 = pkbf(sf[4], sf[5]),   pk3 = pkbf(sf[6], sf[7]);
        uint32_t pk4 = pkbf(sf[8], sf[9]),   pk5 = pkbf(sf[10], sf[11]);
        uint32_t pk6 = pkbf(sf[12], sf[13]), pk7 = pkbf(sf[14], sf[15]);
        uint2v r0 = __builtin_amdgcn_permlane32_swap(pk0, pk2, false, false);
        uint2v r1 = __builtin_amdgcn_permlane32_swap(pk1, pk3, false, false);
        uint2v r2 = __builtin_amdgcn_permlane32_swap(pk4, pk6, false, false);
        uint2v r3 = __builtin_amdgcn_permlane32_swap(pk5, pk7, false, false);
        uint4 u0; u0.x = r0[0]; u0.y = r1[0]; u0.z = r0[1]; u0.w = r1[1];
        uint4 u1; u1.x = r2[0]; u1.y = r3[0]; u1.z = r2[1]; u1.w = r3[1];
        bf16x8 pf0 = __builtin_bit_cast(bf16x8, u0);   // P^T[kv 0..15][q]
        bf16x8 pf1 = __builtin_bit_cast(bf16x8, u1);   // P^T[kv 16..31][q]

        // ---- out^T[c][q] += V . P^T  (linear, conflict-free V reads)
        __builtin_amdgcn_s_setprio(1);
        #pragma unroll
        for (int cb = 0; cb < 8; cb++) {
            bf16x8 v0 = *reinterpret_cast<const bf16x8*>(vbl + (cb * 2 + 0) * 1024);
            acc[cb] = __builtin_amdgcn_mfma_f32_32x32x16_bf16(v0, pf0, acc[cb], 0, 0, 0);
            bf16x8 v1 = *reinterpret_cast<const bf16x8*>(vbl + (cb * 2 + 1) * 1024);
            acc[cb] = __builtin_amdgcn_mfma_f32_32x32x16_bf16(v1, pf1, acc[cb], 0, 0, 0);
        }
        __builtin_amdgcn_s_setprio(0);

        // publish stage(step+1); all K/V reads of buf[cur] complete block-wide
        publish_barrier();
        if (step + 2 < 32) {                    // refill just-consumed buffers
            stageK(step + 2, cur);
            stageV(step + 2, cur);
        }
    }

    // ---- epilogue: per-q-row lsum, write normalized bf16 partial + weight
    lsum += __shfl_xor(lsum, 32);
    float inv = 1.0f / lsum;
    size_t qrow = (size_t)(q0 + m);
    if (h0bf16 || h == 1) {
        unsigned short* myp = h ? part1 : part0;
        #pragma unroll
        for (int cb = 0; cb < 8; cb++)
            #pragma unroll
            for (int q4 = 0; q4 < 4; q4++) {
                int c0i = cb * 32 + q4 * 8 + 4 * hl;
                uint2 u;
                u.x = pkbf(acc[cb][q4 * 4 + 0] * inv, acc[cb][q4 * 4 + 1] * inv);
                u.y = pkbf(acc[cb][q4 * 4 + 2] * inv, acc[cb][q4 * 4 + 3] * inv);
                *reinterpret_cast<uint2*>(myp + qrow * 256 + c0i) = u;
            }
    } else {
        #pragma unroll
        for (int cb = 0; cb < 8; cb++)
            #pragma unroll
            for (int q4 = 0; q4 < 4; q4++) {
                int c0i = cb * 32 + q4 * 8 + 4 * hl;
                float4 o;
                o.x = acc[cb][q4 * 4 + 0] * inv;
                o.y = acc[cb][q4 * 4 + 1] * inv;
                o.z = acc[cb][q4 * 4 + 2] * inv;
                o.w = acc[cb][q4 * 4 + 3] * inv;
                *reinterpret_cast<float4*>(out + qrow * 256 + c0i) = o;
            }
    }
    if (hl == 0) ml[h * BM_ + qrow] = lsum;
}

// ---------------------------------------------------------------- kernel 4
// Merge halves (exact weighted combine) + LayerNorm + LeakyReLU.
// XCD-pinned: block reads the partials its own XCD's flash blocks wrote
// (flash: batches {2x, 2x+1} produced on xcd x; here xcd = blk&7 -> same).
__global__ void merge_ln_kernel(const unsigned short* __restrict__ part0,
                                const unsigned short* __restrict__ part1,
                                const float* __restrict__ ml,
                                const float* __restrict__ gam,
                                const float* __restrict__ bet,
                                float* __restrict__ out,
                                int h0bf16) {
    int w = threadIdx.x >> 6, lane = threadIdx.x & 63;
    int blk = blockIdx.x;                       // 8192
    int xcd = blk & 7, j = blk >> 3;            // j: 0..1023
    int b = 2 * xcd + (j >> 9);
    size_t row = (size_t)b * 2048 + (size_t)(j & 511) * 4 + w;
    float w0 = ml[row], w1 = ml[BM_ + row];
    float rs = 1.0f / (w0 + w1);
    float a0 = w0 * rs, a1 = w1 * rs;
    float4 v;
    ushort4 p1 = *reinterpret_cast<const ushort4*>(part1 + row * 256 + lane * 4);
    if (h0bf16) {
        ushort4 p0 = *reinterpret_cast<const ushort4*>(part0 + row * 256 + lane * 4);
        v.x = a0 * bf2f(p0.x) + a1 * bf2f(p1.x);
        v.y = a0 * bf2f(p0.y) + a1 * bf2f(p1.y);
        v.z = a0 * bf2f(p0.z) + a1 * bf2f(p1.z);
        v.w = a0 * bf2f(p0.w) + a1 * bf2f(p1.w);
    } else {
        float4 o0 = *reinterpret_cast<float4*>(out + row * 256 + lane * 4);
        v.x = a0 * o0.x + a1 * bf2f(p1.x);
        v.y = a0 * o0.y + a1 * bf2f(p1.y);
        v.z = a0 * o0.z + a1 * bf2f(p1.z);
        v.w = a0 * o0.w + a1 * bf2f(p1.w);
    }
    float s = v.x + v.y + v.z + v.w;
    float q = v.x * v.x + v.y * v.y + v.z * v.z + v.w * v.w;
    #pragma unroll
    for (int m = 1; m < 64; m <<= 1) { s += __shfl_xor(s, m); q += __shfl_xor(q, m); }
    float mu = s * (1.0f / 256.0f);
    float var = q * (1.0f / 256.0f) - mu * mu;
    float rstd = rsqrtf(var + 1e-5f);
    float4 gg = *reinterpret_cast<const float4*>(gam + lane * 4);
    float4 bb = *reinterpret_cast<const float4*>(bet + lane * 4);
    float4 o;
    o.x = (v.x - mu) * rstd * gg.x + bb.x;
    o.y = (v.y - mu) * rstd * gg.y + bb.y;
    o.z = (v.z - mu) * rstd * gg.z + bb.z;
    o.w = (v.w - mu) * rstd * gg.w + bb.w;
    o.x = o.x >= 0.f ? o.x : 0.01f * o.x;
    o.y = o.y >= 0.f ? o.y : 0.01f * o.y;
    o.z = o.z >= 0.f ? o.z : 0.01f * o.z;
    o.w = o.w >= 0.f ? o.w : 0.01f * o.w;
    *reinterpret_cast<float4*>(out + row * 256 + lane * 4) = o;
}

// ---------------------------------------------------------------- launcher
extern "C" void kernel_launch(void* const* d_in, const int* in_sizes, int n_in,
                              void* d_out, int out_size, void* d_ws, size_t ws_size,
                              hipStream_t stream) {
    const float* local_feat = (const float*)d_in[0];
    const float* adj_w    = (const float*)d_in[3];
    const float* affine_w = (const float*)d_in[4];
    const float* affine_b = (const float*)d_in[5];
    const float* ln_g     = (const float*)d_in[6];
    const float* ln_b     = (const float*)d_in[7];
    float* out = (float*)d_out;

    char* ws = (char*)d_ws;
    unsigned short* q     = (unsigned short*)(ws);                 // 16 MiB
    unsigned short* v3    = (unsigned short*)(ws + 16777216);      // 16 MiB
    unsigned short* k3    = (unsigned short*)(ws + 33554432);      // 16 MiB
    unsigned short* part1;                                          // 16 MiB
    unsigned short* part0;                                          // 16 MiB (h0bf16 only)
    unsigned short* adjT5;
    unsigned short* affw;
    float*          ml;                                             // 256 KiB

    // primary layout needs 84,148,224 B (known available: r12 ran >= 84.28MB)
    const size_t need = 84148224ull;
    int h0bf16 = (ws_size >= need) ? 1 : 0;
    if (h0bf16) {
        part0 = (unsigned short*)(ws + 50331648);
        part1 = (unsigned short*)(ws + 67108864);
        adjT5 = (unsigned short*)(ws + 83886080);
        affw  = (unsigned short*)(ws + 84017152);
        ml    = (float*)         (ws + 83886080);  // aliases adjT5+affw (dead)
    } else {
        part0 = (unsigned short*)(ws + 50331648);  // unused
        part1 = (unsigned short*)(ws + 50331648);
        adjT5 = (unsigned short*)(ws + 67371008);
        affw  = (unsigned short*)(ws + 67502080);
        ml    = (float*)         (ws + 67108864);  // 256KB before adjT5
    }

    prep_weights<<<256, 256, 0, stream>>>(adj_w, affine_w, adjT5, affw);
    fused_gemm<<<BM_ / 128, 512, 0, stream>>>(local_feat, adjT5, affw, affine_b,
                                              q, v3, k3);
    flash_kernel<<<512, 256, 0, stream>>>(q, k3, v3, out, part0, part1, ml, h0bf16);
    merge_ln_kernel<<<8192, 256, 0, stream>>>(part0, part1, ml, ln_g, ln_b, out, h0bf16);
}

// Round 14
// 128.745 us; speedup vs baseline: 2.6475x; 1.3672x over previous
//
#include <hip/hip_runtime.h>
#include <hip/hip_bf16.h>
#include <stdint.h>

// Shapes (fixed by the problem)
#define B_  16
#define M_  2048            // T*N
#define C_  256
#define BM_ 32768           // B_*M_

typedef __bf16 bf16x8 __attribute__((ext_vector_type(8)));
typedef __bf16 bf16x2 __attribute__((ext_vector_type(2)));
typedef float  f32x4  __attribute__((ext_vector_type(4)));
typedef float  f32x16 __attribute__((ext_vector_type(16)));
typedef unsigned int uint2v __attribute__((ext_vector_type(2)));

__device__ __forceinline__ unsigned short f2bf(float f) {
    uint32_t u = __builtin_bit_cast(uint32_t, f);
    u += 0x7fffu + ((u >> 16) & 1u);          // RNE
    return (unsigned short)(u >> 16);
}

__device__ __forceinline__ uint32_t pkbf(float a, float b) {
    bf16x2 t; t[0] = (__bf16)a; t[1] = (__bf16)b;   // compiler -> v_cvt_pk_bf16_f32
    return __builtin_bit_cast(uint32_t, t);
}

__device__ __forceinline__ float bf2f(unsigned short u) {
    return __builtin_bit_cast(float, ((uint32_t)u) << 16);
}

// async global->LDS, 16B/lane; LDS dest = wave-uniform base, HW adds lane*16
__device__ __forceinline__ void gload16(const void* g, void* l) {
    __builtin_amdgcn_global_load_lds(
        (const __attribute__((address_space(1))) void*)g,
        (__attribute__((address_space(3))) void*)l, 16, 0, 0);
}

// Explicit LDS-DMA publish: drain vmcnt BEFORE the barrier, fence scheduler.
__device__ __forceinline__ void publish_barrier() {
    asm volatile("s_waitcnt vmcnt(0)" ::: "memory");
    __builtin_amdgcn_sched_barrier(0);
    __syncthreads();
    __builtin_amdgcn_sched_barrier(0);
}

// ---------------------------------------------------------------- kernel 1
// adjT5 = 5*log2(e) * adj^T (logits in exp2 domain); affwB = bf16(affine_w)
__global__ void prep_weights(const float* __restrict__ adj,
                             const float* __restrict__ affw,
                             unsigned short* __restrict__ adjT5,
                             unsigned short* __restrict__ affwB) {
    int idx = blockIdx.x * 256 + threadIdx.x;   // 0..65535
    int d = idx >> 8, c = idx & 255;
    adjT5[d * 256 + c] = f2bf(7.2134752f * adj[c * 256 + d]);
    affwB[idx] = f2bf(affw[idx]);
}

// ---------------------------------------------------------------- kernel 2
__global__ void l2norm_kernel(const float* __restrict__ x,
                              unsigned short* __restrict__ nf,
                              float* __restrict__ norms) {
    int w = threadIdx.x >> 6, lane = threadIdx.x & 63;
    int row = blockIdx.x * 4 + w;
    const float4 v = *reinterpret_cast<const float4*>(x + (size_t)row * 256 + lane * 4);
    float ss = v.x * v.x + v.y * v.y + v.z * v.z + v.w * v.w;
    #pragma unroll
    for (int m = 1; m < 64; m <<= 1) ss += __shfl_xor(ss, m);
    float nrm = sqrtf(ss);
    float s = 1.0f / fmaxf(nrm, 1e-12f);
    ushort4 o;
    o.x = f2bf(v.x * s); o.y = f2bf(v.y * s); o.z = f2bf(v.z * s); o.w = f2bf(v.w * s);
    *reinterpret_cast<ushort4*>(nf + (size_t)row * 256 + lane * 4) = o;
    if (lane == 0) norms[row] = nrm;
}

// ---------------------------------------------------------------- kernel 3
// One pass over nf producing Q (row-major), V3 (flash-staging-linear),
// K3 (flash-staging-linear) — r9 version verbatim (proven ~16 us).
__global__ __launch_bounds__(512, 2)
void dual_gemm(const unsigned short* __restrict__ A,
               const unsigned short* __restrict__ B1,
               const unsigned short* __restrict__ B2,
               const float* __restrict__ norms,
               const float* __restrict__ bias,
               unsigned short* __restrict__ outQ,
               unsigned short* __restrict__ outV3,
               unsigned short* __restrict__ outK3) {
    __shared__ unsigned short bb1[256 * 56];
    __shared__ unsigned short bb2[256 * 56];
    int tid = threadIdx.x;
    int w = tid >> 6, lane = tid & 63, g = lane >> 4, r = lane & 15;
    int m0 = blockIdx.x * 128;

    const f32x4 z = {0.f, 0.f, 0.f, 0.f};
    f32x4 accq[16], accv[16];
    #pragma unroll
    for (int i = 0; i < 16; i++) { accq[i] = z; accv[i] = z; }

    int row = m0 + w * 16 + r;
    int kvblk_r = row >> 5, mrow = row & 31;

    for (int dc = 0; dc < 8; dc++) {
        __syncthreads();
        #pragma unroll
        for (int it = 0; it < 2; it++) {
            int n = (w * 2 + it) * 16 + (lane >> 2);
            int t = lane & 3;
            *reinterpret_cast<uint4*>(&bb1[n * 56 + t * 8]) =
                *reinterpret_cast<const uint4*>(B1 + (size_t)n * 256 + dc * 32 + t * 8);
            *reinterpret_cast<uint4*>(&bb2[n * 56 + t * 8]) =
                *reinterpret_cast<const uint4*>(B2 + (size_t)n * 256 + dc * 32 + t * 8);
        }
        __syncthreads();
        bf16x8 af = *reinterpret_cast<const bf16x8*>(
            A + (size_t)row * 256 + dc * 32 + g * 8);
        // K3 store: c-range = dc*32+g*8 -> ch = dc*2+(g>>1), khl = g&1
        {
            int ch = dc * 2 + (g >> 1);
            int khl = g & 1;
            *reinterpret_cast<bf16x8*>(
                outK3 + (size_t)kvblk_r * 8192 + ch * 512 + (khl * 32 + mrow) * 8) = af;
        }
        #pragma unroll
        for (int nf16 = 0; nf16 < 16; nf16++) {
            bf16x8 b1f = *reinterpret_cast<const bf16x8*>(&bb1[(nf16 * 16 + r) * 56 + g * 8]);
            accq[nf16] = __builtin_amdgcn_mfma_f32_16x16x32_bf16(af, b1f, accq[nf16], 0, 0, 0);
            bf16x8 b2f = *reinterpret_cast<const bf16x8*>(&bb2[(nf16 * 16 + r) * 56 + g * 8]);
            accv[nf16] = __builtin_amdgcn_mfma_f32_16x16x32_bf16(af, b2f, accv[nf16], 0, 0, 0);
        }
    }
    // Q epilogue: row-major
    #pragma unroll
    for (int nf16 = 0; nf16 < 16; nf16++) {
        int n = nf16 * 16 + r;
        #pragma unroll
        for (int j = 0; j < 4; j++) {
            int m = m0 + w * 16 + g * 4 + j;
            outQ[(size_t)m * 256 + n] = f2bf(accq[nf16][j]);
        }
    }
    // V3 epilogue: staging-linear layout, * norms + bias
    int mm = m0 + w * 16 + g * 4;               // kv row of acc elem 0 (4-aligned)
    int kvblk = mm >> 5;
    int kv0 = mm & 31;
    int jj  = kv0 >> 4;                         // 16-kv half
    int hl2 = (kv0 >> 3) & 1;                   // 8-kv sub
    int e0  = kv0 & 7;                          // 0 or 4
    float4 nr = *reinterpret_cast<const float4*>(norms + mm);
    #pragma unroll
    for (int nf16 = 0; nf16 < 16; nf16++) {
        int n = nf16 * 16 + r;
        int cb = n >> 5, mr2 = n & 31;
        int slot = (cb * 2 + jj) * 64 + hl2 * 32 + mr2;
        float bv = bias[n];
        ushort4 o;
        o.x = f2bf(accv[nf16][0] * nr.x + bv);
        o.y = f2bf(accv[nf16][1] * nr.y + bv);
        o.z = f2bf(accv[nf16][2] * nr.z + bv);
        o.w = f2bf(accv[nf16][3] * nr.w + bv);
        *reinterpret_cast<ushort4*>(outV3 + (size_t)kvblk * 8192 + slot * 8 + e0) = o;
    }
}

// ---------------------------------------------------------------- kernel 4
// Flash v14 (r13 verbatim): r11 body; epilogue writes bf16 partials for
// BOTH halves when h0bf16 (r12 proved both-halves-bf16 accuracy).
// LDS 64KB: K0@0 K1@16K V0@32K V1@48K -> 2 independent blocks/CU.
__global__ __launch_bounds__(256, 2)
void flash_kernel(const unsigned short* __restrict__ Q,
                  const unsigned short* __restrict__ K3,
                  const unsigned short* __restrict__ V3,
                  float* __restrict__ out,
                  unsigned short* __restrict__ part0,
                  unsigned short* __restrict__ part1,
                  float* __restrict__ ml,
                  int h0bf16) {
    __shared__ __align__(16) char smem[65536];
    const int tid = threadIdx.x;
    const int w = tid >> 6, lane = tid & 63;
    const int hl = lane >> 5, m = lane & 31;    // lane half, lane-in-half
    const int blk = blockIdx.x;
    const int idx = blk >> 3;                   // 0..63
    const int b = (blk & 7) * 2 + (idx >> 5);   // XCD-pinned batch
    const int sub = idx & 31;
    const int mblk = sub >> 1, h = sub & 1;     // q-tile, kv half
    const int q0 = b * M_ + mblk * 128 + w * 32;

    // Q fragments: B-operand; lane holds Q[q0+m][ch*16 + hl*8 ..+8]
    bf16x8 qf[16];
    #pragma unroll
    for (int ch = 0; ch < 16; ch++)
        qf[ch] = *reinterpret_cast<const bf16x8*>(
            Q + (size_t)(q0 + m) * 256 + ch * 16 + hl * 8);

    const f32x16 z16 = {0,0,0,0, 0,0,0,0, 0,0,0,0, 0,0,0,0};
    f32x16 acc[8];
    #pragma unroll
    for (int cb = 0; cb < 8; cb++) acc[cb] = z16;
    float lsum = 0.0f;                          // exp2 domain, fixed max = 0

    // staging sources: fully linear; per-thread base, +8192 ushorts/step
    const unsigned short* Ksrc =
        K3 + ((size_t)(b * 64 + h * 32) * 1024 + tid) * 8;
    const unsigned short* Vsrc =
        V3 + ((size_t)(b * 64 + h * 32) * 1024 + tid) * 8;

    auto stageK = [&](int step, int buf) {
        char* kb = smem + buf * 16384;
        const unsigned short* src = Ksrc + (size_t)step * 8192;
        #pragma unroll
        for (int it = 0; it < 4; it++)
            gload16(src + it * 2048, kb + (it * 256 + w * 64) * 16);
    };
    auto stageV = [&](int step, int buf) {
        char* vb = smem + 32768 + buf * 16384;
        const unsigned short* src = Vsrc + (size_t)step * 8192;
        #pragma unroll
        for (int it = 0; it < 4; it++)
            gload16(src + it * 2048, vb + (it * 256 + w * 64) * 16);
    };

    stageK(0, 0); stageV(0, 0);
    publish_barrier();
    stageK(1, 1); stageV(1, 1);

    for (int step = 0; step < 32; step++) {
        const int cur = step & 1;
        const char* kbl = smem + cur * 16384 + lane * 16;
        const char* vbl = smem + 32768 + cur * 16384 + lane * 16;

        // ---- S^T[32 kv][32 q] = K . Q^T  (linear conflict-free kf reads)
        f32x16 sf = z16;
        __builtin_amdgcn_s_setprio(1);
        #pragma unroll
        for (int ch = 0; ch < 16; ch++) {
            bf16x8 kf = *reinterpret_cast<const bf16x8*>(kbl + ch * 1024);
            sf = __builtin_amdgcn_mfma_f32_32x32x16_bf16(kf, qf[ch], sf, 0, 0, 0);
        }
        __builtin_amdgcn_s_setprio(0);

        // ---- fixed-max softmax: P = exp2(sf)
        #pragma unroll
        for (int i = 0; i < 16; i++) {
            sf[i] = exp2f(sf[i]);
            lsum += sf[i];
        }
        // pack P; lane holds P[q=m][kv=(reg&3)+8*(reg>>2)+4*hl]
        uint32_t pk0 = pkbf(sf[0], sf[1]),   pk1 = pkbf(sf[2], sf[3]);
        uint32_t pk2 = pkbf(sf[4], sf[5]),   pk3 = pkbf(sf[6], sf[7]);
        uint32_t pk4 = pkbf(sf[8], sf[9]),   pk5 = pkbf(sf[10], sf[11]);
        uint32_t pk6 = pkbf(sf[12], sf[13]), pk7 = pkbf(sf[14], sf[15]);
        uint2v r0 = __builtin_amdgcn_permlane32_swap(pk0, pk2, false, false);
        uint2v r1 = __builtin_amdgcn_permlane32_swap(pk1, pk3, false, false);
        uint2v r2 = __builtin_amdgcn_permlane32_swap(pk4, pk6, false, false);
        uint2v r3 = __builtin_amdgcn_permlane32_swap(pk5, pk7, false, false);
        uint4 u0; u0.x = r0[0]; u0.y = r1[0]; u0.z = r0[1]; u0.w = r1[1];
        uint4 u1; u1.x = r2[0]; u1.y = r3[0]; u1.z = r2[1]; u1.w = r3[1];
        bf16x8 pf0 = __builtin_bit_cast(bf16x8, u0);   // P^T[kv 0..15][q]
        bf16x8 pf1 = __builtin_bit_cast(bf16x8, u1);   // P^T[kv 16..31][q]

        // ---- out^T[c][q] += V . P^T  (linear, conflict-free V reads)
        __builtin_amdgcn_s_setprio(1);
        #pragma unroll
        for (int cb = 0; cb < 8; cb++) {
            bf16x8 v0 = *reinterpret_cast<const bf16x8*>(vbl + (cb * 2 + 0) * 1024);
            acc[cb] = __builtin_amdgcn_mfma_f32_32x32x16_bf16(v0, pf0, acc[cb], 0, 0, 0);
            bf16x8 v1 = *reinterpret_cast<const bf16x8*>(vbl + (cb * 2 + 1) * 1024);
            acc[cb] = __builtin_amdgcn_mfma_f32_32x32x16_bf16(v1, pf1, acc[cb], 0, 0, 0);
        }
        __builtin_amdgcn_s_setprio(0);

        // publish stage(step+1); all K/V reads of buf[cur] complete block-wide
        publish_barrier();
        if (step + 2 < 32) {                    // refill just-consumed buffers
            stageK(step + 2, cur);
            stageV(step + 2, cur);
        }
    }

    // ---- epilogue: per-q-row lsum, write normalized bf16 partial + weight
    lsum += __shfl_xor(lsum, 32);
    float inv = 1.0f / lsum;
    size_t qrow = (size_t)(q0 + m);
    if (h0bf16 || h == 1) {
        unsigned short* myp = h ? part1 : part0;
        #pragma unroll
        for (int cb = 0; cb < 8; cb++)
            #pragma unroll
            for (int q4 = 0; q4 < 4; q4++) {
                int c0i = cb * 32 + q4 * 8 + 4 * hl;
                uint2 u;
                u.x = pkbf(acc[cb][q4 * 4 + 0] * inv, acc[cb][q4 * 4 + 1] * inv);
                u.y = pkbf(acc[cb][q4 * 4 + 2] * inv, acc[cb][q4 * 4 + 3] * inv);
                *reinterpret_cast<uint2*>(myp + qrow * 256 + c0i) = u;
            }
    } else {
        #pragma unroll
        for (int cb = 0; cb < 8; cb++)
            #pragma unroll
            for (int q4 = 0; q4 < 4; q4++) {
                int c0i = cb * 32 + q4 * 8 + 4 * hl;
                float4 o;
                o.x = acc[cb][q4 * 4 + 0] * inv;
                o.y = acc[cb][q4 * 4 + 1] * inv;
                o.z = acc[cb][q4 * 4 + 2] * inv;
                o.w = acc[cb][q4 * 4 + 3] * inv;
                *reinterpret_cast<float4*>(out + qrow * 256 + c0i) = o;
            }
    }
    if (hl == 0) ml[h * BM_ + qrow] = lsum;
}

// ---------------------------------------------------------------- kernel 5
// Merge halves (exact weighted combine) + LayerNorm + LeakyReLU.
// XCD-pinned: block reads the partials its own XCD's flash blocks wrote.
__global__ void merge_ln_kernel(const unsigned short* __restrict__ part0,
                                const unsigned short* __restrict__ part1,
                                const float* __restrict__ ml,
                                const float* __restrict__ gam,
                                const float* __restrict__ bet,
                                float* __restrict__ out,
                                int h0bf16) {
    int w = threadIdx.x >> 6, lane = threadIdx.x & 63;
    int blk = blockIdx.x;                       // 8192
    int xcd = blk & 7, j = blk >> 3;            // j: 0..1023
    int b = 2 * xcd + (j >> 9);
    size_t row = (size_t)b * 2048 + (size_t)(j & 511) * 4 + w;
    float w0 = ml[row], w1 = ml[BM_ + row];
    float rs = 1.0f / (w0 + w1);
    float a0 = w0 * rs, a1 = w1 * rs;
    float4 v;
    ushort4 p1 = *reinterpret_cast<const ushort4*>(part1 + row * 256 + lane * 4);
    if (h0bf16) {
        ushort4 p0 = *reinterpret_cast<const ushort4*>(part0 + row * 256 + lane * 4);
        v.x = a0 * bf2f(p0.x) + a1 * bf2f(p1.x);
        v.y = a0 * bf2f(p0.y) + a1 * bf2f(p1.y);
        v.z = a0 * bf2f(p0.z) + a1 * bf2f(p1.z);
        v.w = a0 * bf2f(p0.w) + a1 * bf2f(p1.w);
    } else {
        float4 o0 = *reinterpret_cast<float4*>(out + row * 256 + lane * 4);
        v.x = a0 * o0.x + a1 * bf2f(p1.x);
        v.y = a0 * o0.y + a1 * bf2f(p1.y);
        v.z = a0 * o0.z + a1 * bf2f(p1.z);
        v.w = a0 * o0.w + a1 * bf2f(p1.w);
    }
    float s = v.x + v.y + v.z + v.w;
    float q = v.x * v.x + v.y * v.y + v.z * v.z + v.w * v.w;
    #pragma unroll
    for (int m = 1; m < 64; m <<= 1) { s += __shfl_xor(s, m); q += __shfl_xor(q, m); }
    float mu = s * (1.0f / 256.0f);
    float var = q * (1.0f / 256.0f) - mu * mu;
    float rstd = rsqrtf(var + 1e-5f);
    float4 gg = *reinterpret_cast<const float4*>(gam + lane * 4);
    float4 bb = *reinterpret_cast<const float4*>(bet + lane * 4);
    float4 o;
    o.x = (v.x - mu) * rstd * gg.x + bb.x;
    o.y = (v.y - mu) * rstd * gg.y + bb.y;
    o.z = (v.z - mu) * rstd * gg.z + bb.z;
    o.w = (v.w - mu) * rstd * gg.w + bb.w;
    o.x = o.x >= 0.f ? o.x : 0.01f * o.x;
    o.y = o.y >= 0.f ? o.y : 0.01f * o.y;
    o.z = o.z >= 0.f ? o.z : 0.01f * o.z;
    o.w = o.w >= 0.f ? o.w : 0.01f * o.w;
    *reinterpret_cast<float4*>(out + row * 256 + lane * 4) = o;
}

// ---------------------------------------------------------------- launcher
extern "C" void kernel_launch(void* const* d_in, const int* in_sizes, int n_in,
                              void* d_out, int out_size, void* d_ws, size_t ws_size,
                              hipStream_t stream) {
    const float* local_feat = (const float*)d_in[0];
    const float* adj_w    = (const float*)d_in[3];
    const float* affine_w = (const float*)d_in[4];
    const float* affine_b = (const float*)d_in[5];
    const float* ln_g     = (const float*)d_in[6];
    const float* ln_b     = (const float*)d_in[7];
    float* out = (float*)d_out;

    char* ws = (char*)d_ws;
    unsigned short* nf    = (unsigned short*)(ws);                 // 16 MiB (dead after dual_gemm)
    unsigned short* q     = (unsigned short*)(ws + 16777216);      // 16 MiB
    unsigned short* v3    = (unsigned short*)(ws + 33554432);      // 16 MiB
    unsigned short* k3    = (unsigned short*)(ws + 50331648);      // 16 MiB -> 67108864
    unsigned short* part0 = (unsigned short*)(ws);                 // aliases nf (dead)
    unsigned short* part1;
    unsigned short* adjT5;
    unsigned short* affw;
    float*          norms;
    float*          ml;

    // primary layout high-water = 84,279,296 B (r12 proved >= 84,283,392 B)
    const size_t need = 84279296ull;
    int h0bf16 = (ws_size >= need) ? 1 : 0;
    if (h0bf16) {
        part1 = (unsigned short*)(ws + 67108864);  // 16 MiB -> 83886080
        adjT5 = (unsigned short*)(ws + 83886080);  // 128 KiB
        affw  = (unsigned short*)(ws + 84017152);  // 128 KiB
        norms = (float*)         (ws + 84148224);  // 128 KiB -> 84279296
        ml    = (float*)         (ws + 83886080);  // aliases adjT5+affw (dead)
    } else {
        part1 = (unsigned short*)(ws);             // aliases nf (part0 unused)
        adjT5 = (unsigned short*)(ws + 67108864);  // 128 KiB
        affw  = (unsigned short*)(ws + 67239936);  // 128 KiB
        norms = (float*)         (ws + 67371008);  // 128 KiB -> 67502080 (r9-proven)
        ml    = (float*)         (ws + 67108864);  // aliases adjT5+affw (dead)
    }

    prep_weights<<<256, 256, 0, stream>>>(adj_w, affine_w, adjT5, affw);
    l2norm_kernel<<<BM_ / 4, 256, 0, stream>>>(local_feat, nf, norms);
    dual_gemm<<<BM_ / 128, 512, 0, stream>>>(nf, adjT5, affw, norms, affine_b, q, v3, k3);
    flash_kernel<<<512, 256, 0, stream>>>(q, k3, v3, out, part0, part1, ml, h0bf16);
    merge_ln_kernel<<<8192, 256, 0, stream>>>(part0, part1, ml, ln_g, ln_b, out, h0bf16);
}

// Round 15
// 124.546 us; speedup vs baseline: 2.7368x; 1.0337x over previous
//
#include <hip/hip_runtime.h>
#include <hip/hip_bf16.h>
#include <stdint.h>

// Shapes (fixed by the problem)
#define B_  16
#define M_  2048            // T*N
#define C_  256
#define BM_ 32768           // B_*M_

typedef __bf16 bf16x8 __attribute__((ext_vector_type(8)));
typedef __bf16 bf16x2 __attribute__((ext_vector_type(2)));
typedef float  f32x4  __attribute__((ext_vector_type(4)));
typedef float  f32x16 __attribute__((ext_vector_type(16)));
typedef unsigned int uint2v __attribute__((ext_vector_type(2)));

__device__ __forceinline__ unsigned short f2bf(float f) {
    uint32_t u = __builtin_bit_cast(uint32_t, f);
    u += 0x7fffu + ((u >> 16) & 1u);          // RNE
    return (unsigned short)(u >> 16);
}

__device__ __forceinline__ uint32_t pkbf(float a, float b) {
    bf16x2 t; t[0] = (__bf16)a; t[1] = (__bf16)b;   // compiler -> v_cvt_pk_bf16_f32
    return __builtin_bit_cast(uint32_t, t);
}

__device__ __forceinline__ float bf2f(unsigned short u) {
    return __builtin_bit_cast(float, ((uint32_t)u) << 16);
}

// async global->LDS, 16B/lane; LDS dest = wave-uniform base, HW adds lane*16
__device__ __forceinline__ void gload16(const void* g, void* l) {
    __builtin_amdgcn_global_load_lds(
        (const __attribute__((address_space(1))) void*)g,
        (__attribute__((address_space(3))) void*)l, 16, 0, 0);
}

// Explicit LDS-DMA publish: drain vmcnt BEFORE the barrier, fence scheduler.
__device__ __forceinline__ void publish_barrier() {
    asm volatile("s_waitcnt vmcnt(0)" ::: "memory");
    __builtin_amdgcn_sched_barrier(0);
    __syncthreads();
    __builtin_amdgcn_sched_barrier(0);
}

// ---------------------------------------------------------------- kernel 1
// FUSED: blocks 0..8191 = l2norm; blocks 8192..8447 = weight prep.
__global__ void l2norm_prep_kernel(const float* __restrict__ x,
                                   unsigned short* __restrict__ nf,
                                   float* __restrict__ norms,
                                   const float* __restrict__ adj,
                                   const float* __restrict__ affw,
                                   unsigned short* __restrict__ adjT5,
                                   unsigned short* __restrict__ affwB) {
    if (blockIdx.x >= 8192) {                   // prep part
        int idx = (blockIdx.x - 8192) * 256 + threadIdx.x;
        int d = idx >> 8, c = idx & 255;
        adjT5[d * 256 + c] = f2bf(7.2134752f * adj[c * 256 + d]);
        affwB[idx] = f2bf(affw[idx]);
        return;
    }
    int w = threadIdx.x >> 6, lane = threadIdx.x & 63;
    int row = blockIdx.x * 4 + w;
    const float4 v = *reinterpret_cast<const float4*>(x + (size_t)row * 256 + lane * 4);
    float ss = v.x * v.x + v.y * v.y + v.z * v.z + v.w * v.w;
    #pragma unroll
    for (int m = 1; m < 64; m <<= 1) ss += __shfl_xor(ss, m);
    float nrm = sqrtf(ss);
    float s = 1.0f / fmaxf(nrm, 1e-12f);
    ushort4 o;
    o.x = f2bf(v.x * s); o.y = f2bf(v.y * s); o.z = f2bf(v.z * s); o.w = f2bf(v.w * s);
    *reinterpret_cast<ushort4*>(nf + (size_t)row * 256 + lane * 4) = o;
    if (lane == 0) norms[row] = nrm;
}

// ---------------------------------------------------------------- kernel 2
// One pass over nf producing Q (row-major), V3 (flash-staging-linear),
// K3 (flash-staging-linear) — r9 version verbatim.
__global__ __launch_bounds__(512, 2)
void dual_gemm(const unsigned short* __restrict__ A,
               const unsigned short* __restrict__ B1,
               const unsigned short* __restrict__ B2,
               const float* __restrict__ norms,
               const float* __restrict__ bias,
               unsigned short* __restrict__ outQ,
               unsigned short* __restrict__ outV3,
               unsigned short* __restrict__ outK3) {
    __shared__ unsigned short bb1[256 * 56];
    __shared__ unsigned short bb2[256 * 56];
    int tid = threadIdx.x;
    int w = tid >> 6, lane = tid & 63, g = lane >> 4, r = lane & 15;
    int m0 = blockIdx.x * 128;

    const f32x4 z = {0.f, 0.f, 0.f, 0.f};
    f32x4 accq[16], accv[16];
    #pragma unroll
    for (int i = 0; i < 16; i++) { accq[i] = z; accv[i] = z; }

    int row = m0 + w * 16 + r;
    int kvblk_r = row >> 5, mrow = row & 31;

    for (int dc = 0; dc < 8; dc++) {
        __syncthreads();
        #pragma unroll
        for (int it = 0; it < 2; it++) {
            int n = (w * 2 + it) * 16 + (lane >> 2);
            int t = lane & 3;
            *reinterpret_cast<uint4*>(&bb1[n * 56 + t * 8]) =
                *reinterpret_cast<const uint4*>(B1 + (size_t)n * 256 + dc * 32 + t * 8);
            *reinterpret_cast<uint4*>(&bb2[n * 56 + t * 8]) =
                *reinterpret_cast<const uint4*>(B2 + (size_t)n * 256 + dc * 32 + t * 8);
        }
        __syncthreads();
        bf16x8 af = *reinterpret_cast<const bf16x8*>(
            A + (size_t)row * 256 + dc * 32 + g * 8);
        // K3 store: c-range = dc*32+g*8 -> ch = dc*2+(g>>1), khl = g&1
        {
            int ch = dc * 2 + (g >> 1);
            int khl = g & 1;
            *reinterpret_cast<bf16x8*>(
                outK3 + (size_t)kvblk_r * 8192 + ch * 512 + (khl * 32 + mrow) * 8) = af;
        }
        #pragma unroll
        for (int nf16 = 0; nf16 < 16; nf16++) {
            bf16x8 b1f = *reinterpret_cast<const bf16x8*>(&bb1[(nf16 * 16 + r) * 56 + g * 8]);
            accq[nf16] = __builtin_amdgcn_mfma_f32_16x16x32_bf16(af, b1f, accq[nf16], 0, 0, 0);
            bf16x8 b2f = *reinterpret_cast<const bf16x8*>(&bb2[(nf16 * 16 + r) * 56 + g * 8]);
            accv[nf16] = __builtin_amdgcn_mfma_f32_16x16x32_bf16(af, b2f, accv[nf16], 0, 0, 0);
        }
    }
    // Q epilogue: row-major
    #pragma unroll
    for (int nf16 = 0; nf16 < 16; nf16++) {
        int n = nf16 * 16 + r;
        #pragma unroll
        for (int j = 0; j < 4; j++) {
            int m = m0 + w * 16 + g * 4 + j;
            outQ[(size_t)m * 256 + n] = f2bf(accq[nf16][j]);
        }
    }
    // V3 epilogue: staging-linear layout, * norms + bias
    int mm = m0 + w * 16 + g * 4;               // kv row of acc elem 0 (4-aligned)
    int kvblk = mm >> 5;
    int kv0 = mm & 31;
    int jj  = kv0 >> 4;                         // 16-kv half
    int hl2 = (kv0 >> 3) & 1;                   // 8-kv sub
    int e0  = kv0 & 7;                          // 0 or 4
    float4 nr = *reinterpret_cast<const float4*>(norms + mm);
    #pragma unroll
    for (int nf16 = 0; nf16 < 16; nf16++) {
        int n = nf16 * 16 + r;
        int cb = n >> 5, mr2 = n & 31;
        int slot = (cb * 2 + jj) * 64 + hl2 * 32 + mr2;
        float bv = bias[n];
        ushort4 o;
        o.x = f2bf(accv[nf16][0] * nr.x + bv);
        o.y = f2bf(accv[nf16][1] * nr.y + bv);
        o.z = f2bf(accv[nf16][2] * nr.z + bv);
        o.w = f2bf(accv[nf16][3] * nr.w + bv);
        *reinterpret_cast<ushort4*>(outV3 + (size_t)kvblk * 8192 + slot * 8 + e0) = o;
    }
}

// ---------------------------------------------------------------- kernel 3
// Flash v15: PV-after-barrier software pipeline. Per iteration:
//   publish_barrier -> stage(s+2) -> PV(s) ∥ QK(s+1)+SM(s+1)
// PV's 8 independent acc chains fill QK's 16-deep serial chain bubbles.
// V TRIPLE-buffered (PV(s) reads V[s%3] one step after publish; stage(s+3)
// writes it only after barrier(s+1) -> race-free). K double-buffered.
// LDS 80KB: K0@0 K1@16K V0@32K V1@48K V2@64K; 2 blocks/CU = 160KB exactly.
__global__ __launch_bounds__(256, 2)
void flash_kernel(const unsigned short* __restrict__ Q,
                  const unsigned short* __restrict__ K3,
                  const unsigned short* __restrict__ V3,
                  float* __restrict__ out,
                  unsigned short* __restrict__ part0,
                  unsigned short* __restrict__ part1,
                  float* __restrict__ ml,
                  int h0bf16) {
    __shared__ __align__(16) char smem[81920];
    const int tid = threadIdx.x;
    const int w = tid >> 6, lane = tid & 63;
    const int hl = lane >> 5, m = lane & 31;    // lane half, lane-in-half
    const int blk = blockIdx.x;
    const int idx = blk >> 3;                   // 0..63
    const int b = (blk & 7) * 2 + (idx >> 5);   // XCD-pinned batch
    const int sub = idx & 31;
    const int mblk = sub >> 1, h = sub & 1;     // q-tile, kv half
    const int q0 = b * M_ + mblk * 128 + w * 32;

    // Q fragments: B-operand; lane holds Q[q0+m][ch*16 + hl*8 ..+8]
    bf16x8 qf[16];
    #pragma unroll
    for (int ch = 0; ch < 16; ch++)
        qf[ch] = *reinterpret_cast<const bf16x8*>(
            Q + (size_t)(q0 + m) * 256 + ch * 16 + hl * 8);

    const f32x16 z16 = {0,0,0,0, 0,0,0,0, 0,0,0,0, 0,0,0,0};
    f32x16 acc[8];
    #pragma unroll
    for (int cb = 0; cb < 8; cb++) acc[cb] = z16;
    float lsum = 0.0f;                          // exp2 domain, fixed max = 0

    // staging sources: fully linear; per-thread base, +8192 ushorts/step
    const unsigned short* Ksrc =
        K3 + ((size_t)(b * 64 + h * 32) * 1024 + tid) * 8;
    const unsigned short* Vsrc =
        V3 + ((size_t)(b * 64 + h * 32) * 1024 + tid) * 8;

    auto stageK = [&](int step, int buf) {
        char* kb = smem + buf * 16384;
        const unsigned short* src = Ksrc + (size_t)step * 8192;
        #pragma unroll
        for (int it = 0; it < 4; it++)
            gload16(src + it * 2048, kb + (it * 256 + w * 64) * 16);
    };
    auto stageV = [&](int step, int buf) {
        char* vb = smem + 32768 + buf * 16384;
        const unsigned short* src = Vsrc + (size_t)step * 8192;
        #pragma unroll
        for (int it = 0; it < 4; it++)
            gload16(src + it * 2048, vb + (it * 256 + w * 64) * 16);
    };

    bf16x8 pf0, pf1;                            // P^T frags, carried across barrier
    auto qksm = [&](int s) {
        const char* kbl = smem + (s & 1) * 16384 + lane * 16;
        f32x16 sf = z16;
        __builtin_amdgcn_s_setprio(1);
        #pragma unroll
        for (int ch = 0; ch < 16; ch++) {
            bf16x8 kf = *reinterpret_cast<const bf16x8*>(kbl + ch * 1024);
            sf = __builtin_amdgcn_mfma_f32_32x32x16_bf16(kf, qf[ch], sf, 0, 0, 0);
        }
        __builtin_amdgcn_s_setprio(0);
        #pragma unroll
        for (int i = 0; i < 16; i++) {          // fixed-max: P = exp2(sf)
            sf[i] = exp2f(sf[i]);
            lsum += sf[i];
        }
        uint32_t pk0 = pkbf(sf[0], sf[1]),   pk1 = pkbf(sf[2], sf[3]);
        uint32_t pk2 = pkbf(sf[4], sf[5]),   pk3 = pkbf(sf[6], sf[7]);
        uint32_t pk4 = pkbf(sf[8], sf[9]),   pk5 = pkbf(sf[10], sf[11]);
        uint32_t pk6 = pkbf(sf[12], sf[13]), pk7 = pkbf(sf[14], sf[15]);
        uint2v r0 = __builtin_amdgcn_permlane32_swap(pk0, pk2, false, false);
        uint2v r1 = __builtin_amdgcn_permlane32_swap(pk1, pk3, false, false);
        uint2v r2 = __builtin_amdgcn_permlane32_swap(pk4, pk6, false, false);
        uint2v r3 = __builtin_amdgcn_permlane32_swap(pk5, pk7, false, false);
        uint4 u0; u0.x = r0[0]; u0.y = r1[0]; u0.z = r0[1]; u0.w = r1[1];
        uint4 u1; u1.x = r2[0]; u1.y = r3[0]; u1.z = r2[1]; u1.w = r3[1];
        pf0 = __builtin_bit_cast(bf16x8, u0);   // P^T[kv 0..15][q]
        pf1 = __builtin_bit_cast(bf16x8, u1);   // P^T[kv 16..31][q]
    };

    stageK(0, 0); stageV(0, 0);
    publish_barrier();                          // K0,V0 ready
    stageK(1, 1); stageV(1, 1);
    qksm(0);                                    // QK(0)+SM(0) reads K0

    int vcur = 0;                               // V buffer of step s
    for (int s = 0; s < 32; s++) {
        publish_barrier();                      // publishes stage(s+1)
        if (s + 2 < 32) {
            int vst = vcur + 2; if (vst >= 3) vst -= 3;
            stageK(s + 2, s & 1);               // K[s&1]: QK(s) done pre-barrier
            stageV(s + 2, vst);                 // V[(s+2)%3]: PV(s-1) done pre-barrier
        }
        // ---- PV(s) reads V[s%3]; QK(s+1) interleaves on the MFMA pipe
        const char* vbl = smem + 32768 + vcur * 16384 + lane * 16;
        bf16x8 p0 = pf0, p1 = pf1;
        __builtin_amdgcn_s_setprio(1);
        #pragma unroll
        for (int cb = 0; cb < 8; cb++) {
            bf16x8 v0 = *reinterpret_cast<const bf16x8*>(vbl + (cb * 2 + 0) * 1024);
            acc[cb] = __builtin_amdgcn_mfma_f32_32x32x16_bf16(v0, p0, acc[cb], 0, 0, 0);
            bf16x8 v1 = *reinterpret_cast<const bf16x8*>(vbl + (cb * 2 + 1) * 1024);
            acc[cb] = __builtin_amdgcn_mfma_f32_32x32x16_bf16(v1, p1, acc[cb], 0, 0, 0);
        }
        __builtin_amdgcn_s_setprio(0);
        if (s + 1 < 32) qksm(s + 1);            // reads K[(s+1)&1] (just published)
        vcur++; if (vcur >= 3) vcur -= 3;
    }

    // ---- epilogue: per-q-row lsum, write normalized bf16 partial + weight
    lsum += __shfl_xor(lsum, 32);
    float inv = 1.0f / lsum;
    size_t qrow = (size_t)(q0 + m);
    if (h0bf16 || h == 1) {
        unsigned short* myp = h ? part1 : part0;
        #pragma unroll
        for (int cb = 0; cb < 8; cb++)
            #pragma unroll
            for (int q4 = 0; q4 < 4; q4++) {
                int c0i = cb * 32 + q4 * 8 + 4 * hl;
                uint2 u;
                u.x = pkbf(acc[cb][q4 * 4 + 0] * inv, acc[cb][q4 * 4 + 1] * inv);
                u.y = pkbf(acc[cb][q4 * 4 + 2] * inv, acc[cb][q4 * 4 + 3] * inv);
                *reinterpret_cast<uint2*>(myp + qrow * 256 + c0i) = u;
            }
    } else {
        #pragma unroll
        for (int cb = 0; cb < 8; cb++)
            #pragma unroll
            for (int q4 = 0; q4 < 4; q4++) {
                int c0i = cb * 32 + q4 * 8 + 4 * hl;
                float4 o;
                o.x = acc[cb][q4 * 4 + 0] * inv;
                o.y = acc[cb][q4 * 4 + 1] * inv;
                o.z = acc[cb][q4 * 4 + 2] * inv;
                o.w = acc[cb][q4 * 4 + 3] * inv;
                *reinterpret_cast<float4*>(out + qrow * 256 + c0i) = o;
            }
    }
    if (hl == 0) ml[h * BM_ + qrow] = lsum;
}

// ---------------------------------------------------------------- kernel 4
// Merge halves (exact weighted combine) + LayerNorm + LeakyReLU.
// XCD-pinned: block reads the partials its own XCD's flash blocks wrote.
__global__ void merge_ln_kernel(const unsigned short* __restrict__ part0,
                                const unsigned short* __restrict__ part1,
                                const float* __restrict__ ml,
                                const float* __restrict__ gam,
                                const float* __restrict__ bet,
                                float* __restrict__ out,
                                int h0bf16) {
    int w = threadIdx.x >> 6, lane = threadIdx.x & 63;
    int blk = blockIdx.x;                       // 8192
    int xcd = blk & 7, j = blk >> 3;            // j: 0..1023
    int b = 2 * xcd + (j >> 9);
    size_t row = (size_t)b * 2048 + (size_t)(j & 511) * 4 + w;
    float w0 = ml[row], w1 = ml[BM_ + row];
    float rs = 1.0f / (w0 + w1);
    float a0 = w0 * rs, a1 = w1 * rs;
    float4 v;
    ushort4 p1 = *reinterpret_cast<const ushort4*>(part1 + row * 256 + lane * 4);
    if (h0bf16) {
        ushort4 p0 = *reinterpret_cast<const ushort4*>(part0 + row * 256 + lane * 4);
        v.x = a0 * bf2f(p0.x) + a1 * bf2f(p1.x);
        v.y = a0 * bf2f(p0.y) + a1 * bf2f(p1.y);
        v.z = a0 * bf2f(p0.z) + a1 * bf2f(p1.z);
        v.w = a0 * bf2f(p0.w) + a1 * bf2f(p1.w);
    } else {
        float4 o0 = *reinterpret_cast<float4*>(out + row * 256 + lane * 4);
        v.x = a0 * o0.x + a1 * bf2f(p1.x);
        v.y = a0 * o0.y + a1 * bf2f(p1.y);
        v.z = a0 * o0.z + a1 * bf2f(p1.z);
        v.w = a0 * o0.w + a1 * bf2f(p1.w);
    }
    float s = v.x + v.y + v.z + v.w;
    float q = v.x * v.x + v.y * v.y + v.z * v.z + v.w * v.w;
    #pragma unroll
    for (int m = 1; m < 64; m <<= 1) { s += __shfl_xor(s, m); q += __shfl_xor(q, m); }
    float mu = s * (1.0f / 256.0f);
    float var = q * (1.0f / 256.0f) - mu * mu;
    float rstd = rsqrtf(var + 1e-5f);
    float4 gg = *reinterpret_cast<const float4*>(gam + lane * 4);
    float4 bb = *reinterpret_cast<const float4*>(bet + lane * 4);
    float4 o;
    o.x = (v.x - mu) * rstd * gg.x + bb.x;
    o.y = (v.y - mu) * rstd * gg.y + bb.y;
    o.z = (v.z - mu) * rstd * gg.z + bb.z;
    o.w = (v.w - mu) * rstd * gg.w + bb.w;
    o.x = o.x >= 0.f ? o.x : 0.01f * o.x;
    o.y = o.y >= 0.f ? o.y : 0.01f * o.y;
    o.z = o.z >= 0.f ? o.z : 0.01f * o.z;
    o.w = o.w >= 0.f ? o.w : 0.01f * o.w;
    *reinterpret_cast<float4*>(out + row * 256 + lane * 4) = o;
}

// ---------------------------------------------------------------- launcher
extern "C" void kernel_launch(void* const* d_in, const int* in_sizes, int n_in,
                              void* d_out, int out_size, void* d_ws, size_t ws_size,
                              hipStream_t stream) {
    const float* local_feat = (const float*)d_in[0];
    const float* adj_w    = (const float*)d_in[3];
    const float* affine_w = (const float*)d_in[4];
    const float* affine_b = (const float*)d_in[5];
    const float* ln_g     = (const float*)d_in[6];
    const float* ln_b     = (const float*)d_in[7];
    float* out = (float*)d_out;

    char* ws = (char*)d_ws;
    unsigned short* nf    = (unsigned short*)(ws);                 // 16 MiB (dead after dual_gemm)
    unsigned short* q     = (unsigned short*)(ws + 16777216);      // 16 MiB
    unsigned short* v3    = (unsigned short*)(ws + 33554432);      // 16 MiB
    unsigned short* k3    = (unsigned short*)(ws + 50331648);      // 16 MiB -> 67108864
    unsigned short* part0 = (unsigned short*)(ws);                 // aliases nf (dead)
    unsigned short* part1;
    unsigned short* adjT5;
    unsigned short* affw;
    float*          norms;
    float*          ml;

    // primary layout high-water = 84,279,296 B (r12 proved >= 84,283,392 B)
    const size_t need = 84279296ull;
    int h0bf16 = (ws_size >= need) ? 1 : 0;
    if (h0bf16) {
        part1 = (unsigned short*)(ws + 67108864);  // 16 MiB -> 83886080
        adjT5 = (unsigned short*)(ws + 83886080);  // 128 KiB
        affw  = (unsigned short*)(ws + 84017152);  // 128 KiB
        norms = (float*)         (ws + 84148224);  // 128 KiB -> 84279296
        ml    = (float*)         (ws + 83886080);  // aliases adjT5+affw (dead)
    } else {
        part1 = (unsigned short*)(ws);             // aliases nf (part0 unused)
        adjT5 = (unsigned short*)(ws + 67108864);  // 128 KiB
        affw  = (unsigned short*)(ws + 67239936);  // 128 KiB
        norms = (float*)         (ws + 67371008);  // 128 KiB -> 67502080 (r9-proven)
        ml    = (float*)         (ws + 67108864);  // aliases adjT5+affw (dead)
    }

    l2norm_prep_kernel<<<8448, 256, 0, stream>>>(local_feat, nf, norms,
                                                 adj_w, affine_w, adjT5, affw);
    dual_gemm<<<BM_ / 128, 512, 0, stream>>>(nf, adjT5, affw, norms, affine_b, q, v3, k3);
    flash_kernel<<<512, 256, 0, stream>>>(q, k3, v3, out, part0, part1, ml, h0bf16);
    merge_ln_kernel<<<8192, 256, 0, stream>>>(part0, part1, ml, ln_g, ln_b, out, h0bf16);
}

// Round 16
// 123.845 us; speedup vs baseline: 2.7523x; 1.0057x over previous
//
#include <hip/hip_runtime.h>
#include <hip/hip_bf16.h>
#include <stdint.h>

// Shapes (fixed by the problem)
#define B_  16
#define M_  2048            // T*N
#define C_  256
#define BM_ 32768           // B_*M_

typedef __bf16 bf16x8 __attribute__((ext_vector_type(8)));
typedef __bf16 bf16x2 __attribute__((ext_vector_type(2)));
typedef float  f32x4  __attribute__((ext_vector_type(4)));
typedef float  f32x16 __attribute__((ext_vector_type(16)));
typedef unsigned int uint2v __attribute__((ext_vector_type(2)));

__device__ __forceinline__ unsigned short f2bf(float f) {
    uint32_t u = __builtin_bit_cast(uint32_t, f);
    u += 0x7fffu + ((u >> 16) & 1u);          // RNE
    return (unsigned short)(u >> 16);
}

__device__ __forceinline__ uint32_t pkbf(float a, float b) {
    bf16x2 t; t[0] = (__bf16)a; t[1] = (__bf16)b;   // compiler -> v_cvt_pk_bf16_f32
    return __builtin_bit_cast(uint32_t, t);
}

__device__ __forceinline__ float bf2f(unsigned short u) {
    return __builtin_bit_cast(float, ((uint32_t)u) << 16);
}

// async global->LDS, 16B/lane; LDS dest = wave-uniform base, HW adds lane*16
__device__ __forceinline__ void gload16(const void* g, void* l) {
    __builtin_amdgcn_global_load_lds(
        (const __attribute__((address_space(1))) void*)g,
        (__attribute__((address_space(3))) void*)l, 16, 0, 0);
}

// Explicit LDS-DMA publish: drain vmcnt BEFORE the barrier, fence scheduler.
__device__ __forceinline__ void publish_barrier() {
    asm volatile("s_waitcnt vmcnt(0)" ::: "memory");
    __builtin_amdgcn_sched_barrier(0);
    __syncthreads();
    __builtin_amdgcn_sched_barrier(0);
}

// ---------------------------------------------------------------- kernel 1
// FUSED: blocks 0..8191 = l2norm; blocks 8192..8447 = weight prep.
__global__ void l2norm_prep_kernel(const float* __restrict__ x,
                                   unsigned short* __restrict__ nf,
                                   float* __restrict__ norms,
                                   const float* __restrict__ adj,
                                   const float* __restrict__ affw,
                                   unsigned short* __restrict__ adjT5,
                                   unsigned short* __restrict__ affwB) {
    if (blockIdx.x >= 8192) {                   // prep part
        int idx = (blockIdx.x - 8192) * 256 + threadIdx.x;
        int d = idx >> 8, c = idx & 255;
        adjT5[d * 256 + c] = f2bf(7.2134752f * adj[c * 256 + d]);
        affwB[idx] = f2bf(affw[idx]);
        return;
    }
    int w = threadIdx.x >> 6, lane = threadIdx.x & 63;
    int row = blockIdx.x * 4 + w;
    const float4 v = *reinterpret_cast<const float4*>(x + (size_t)row * 256 + lane * 4);
    float ss = v.x * v.x + v.y * v.y + v.z * v.z + v.w * v.w;
    #pragma unroll
    for (int m = 1; m < 64; m <<= 1) ss += __shfl_xor(ss, m);
    float nrm = sqrtf(ss);
    float s = 1.0f / fmaxf(nrm, 1e-12f);
    ushort4 o;
    o.x = f2bf(v.x * s); o.y = f2bf(v.y * s); o.z = f2bf(v.z * s); o.w = f2bf(v.w * s);
    *reinterpret_cast<ushort4*>(nf + (size_t)row * 256 + lane * 4) = o;
    if (lane == 0) norms[row] = nrm;
}

// ---------------------------------------------------------------- kernel 2
// One pass over nf producing Q (row-major), V3 (flash-staging-linear),
// K3 (flash-staging-linear) — r9 version verbatim.
__global__ __launch_bounds__(512, 2)
void dual_gemm(const unsigned short* __restrict__ A,
               const unsigned short* __restrict__ B1,
               const unsigned short* __restrict__ B2,
               const float* __restrict__ norms,
               const float* __restrict__ bias,
               unsigned short* __restrict__ outQ,
               unsigned short* __restrict__ outV3,
               unsigned short* __restrict__ outK3) {
    __shared__ unsigned short bb1[256 * 56];
    __shared__ unsigned short bb2[256 * 56];
    int tid = threadIdx.x;
    int w = tid >> 6, lane = tid & 63, g = lane >> 4, r = lane & 15;
    int m0 = blockIdx.x * 128;

    const f32x4 z = {0.f, 0.f, 0.f, 0.f};
    f32x4 accq[16], accv[16];
    #pragma unroll
    for (int i = 0; i < 16; i++) { accq[i] = z; accv[i] = z; }

    int row = m0 + w * 16 + r;
    int kvblk_r = row >> 5, mrow = row & 31;

    for (int dc = 0; dc < 8; dc++) {
        __syncthreads();
        #pragma unroll
        for (int it = 0; it < 2; it++) {
            int n = (w * 2 + it) * 16 + (lane >> 2);
            int t = lane & 3;
            *reinterpret_cast<uint4*>(&bb1[n * 56 + t * 8]) =
                *reinterpret_cast<const uint4*>(B1 + (size_t)n * 256 + dc * 32 + t * 8);
            *reinterpret_cast<uint4*>(&bb2[n * 56 + t * 8]) =
                *reinterpret_cast<const uint4*>(B2 + (size_t)n * 256 + dc * 32 + t * 8);
        }
        __syncthreads();
        bf16x8 af = *reinterpret_cast<const bf16x8*>(
            A + (size_t)row * 256 + dc * 32 + g * 8);
        // K3 store: c-range = dc*32+g*8 -> ch = dc*2+(g>>1), khl = g&1
        {
            int ch = dc * 2 + (g >> 1);
            int khl = g & 1;
            *reinterpret_cast<bf16x8*>(
                outK3 + (size_t)kvblk_r * 8192 + ch * 512 + (khl * 32 + mrow) * 8) = af;
        }
        #pragma unroll
        for (int nf16 = 0; nf16 < 16; nf16++) {
            bf16x8 b1f = *reinterpret_cast<const bf16x8*>(&bb1[(nf16 * 16 + r) * 56 + g * 8]);
            accq[nf16] = __builtin_amdgcn_mfma_f32_16x16x32_bf16(af, b1f, accq[nf16], 0, 0, 0);
            bf16x8 b2f = *reinterpret_cast<const bf16x8*>(&bb2[(nf16 * 16 + r) * 56 + g * 8]);
            accv[nf16] = __builtin_amdgcn_mfma_f32_16x16x32_bf16(af, b2f, accv[nf16], 0, 0, 0);
        }
    }
    // Q epilogue: row-major
    #pragma unroll
    for (int nf16 = 0; nf16 < 16; nf16++) {
        int n = nf16 * 16 + r;
        #pragma unroll
        for (int j = 0; j < 4; j++) {
            int m = m0 + w * 16 + g * 4 + j;
            outQ[(size_t)m * 256 + n] = f2bf(accq[nf16][j]);
        }
    }
    // V3 epilogue: staging-linear layout, * norms + bias
    int mm = m0 + w * 16 + g * 4;               // kv row of acc elem 0 (4-aligned)
    int kvblk = mm >> 5;
    int kv0 = mm & 31;
    int jj  = kv0 >> 4;                         // 16-kv half
    int hl2 = (kv0 >> 3) & 1;                   // 8-kv sub
    int e0  = kv0 & 7;                          // 0 or 4
    float4 nr = *reinterpret_cast<const float4*>(norms + mm);
    #pragma unroll
    for (int nf16 = 0; nf16 < 16; nf16++) {
        int n = nf16 * 16 + r;
        int cb = n >> 5, mr2 = n & 31;
        int slot = (cb * 2 + jj) * 64 + hl2 * 32 + mr2;
        float bv = bias[n];
        ushort4 o;
        o.x = f2bf(accv[nf16][0] * nr.x + bv);
        o.y = f2bf(accv[nf16][1] * nr.y + bv);
        o.z = f2bf(accv[nf16][2] * nr.z + bv);
        o.w = f2bf(accv[nf16][3] * nr.w + bv);
        *reinterpret_cast<ushort4*>(outV3 + (size_t)kvblk * 8192 + slot * 8 + e0) = o;
    }
}

// ---------------------------------------------------------------- kernel 3
// Flash v16 = r15 pipeline + ANTI-PHASE STAGGER: co-resident blocks are
// (j, j+256) under XCD round-robin + linear fill; blocks >= 256 sleep
// ~half a step (s_sleep 49 ~ 3136 cyc) before starting, so the two blocks
// on each CU run anti-phased (block A's softmax/VALU overlaps block B's
// LDS/MFMA burst). Anti-phase is a stable equilibrium under symmetric
// LDS contention. Zero correctness impact (pure delay).
// LDS 80KB: K0@0 K1@16K V0@32K V1@48K V2@64K; 2 blocks/CU = 160KB exactly.
__global__ __launch_bounds__(256, 2)
void flash_kernel(const unsigned short* __restrict__ Q,
                  const unsigned short* __restrict__ K3,
                  const unsigned short* __restrict__ V3,
                  float* __restrict__ out,
                  unsigned short* __restrict__ part0,
                  unsigned short* __restrict__ part1,
                  float* __restrict__ ml,
                  int h0bf16) {
    __shared__ __align__(16) char smem[81920];
    const int tid = threadIdx.x;
    const int w = tid >> 6, lane = tid & 63;
    const int hl = lane >> 5, m = lane & 31;    // lane half, lane-in-half
    const int blk = blockIdx.x;
    const int idx = blk >> 3;                   // 0..63
    const int b = (blk & 7) * 2 + (idx >> 5);   // XCD-pinned batch
    const int sub = idx & 31;
    const int mblk = sub >> 1, h = sub & 1;     // q-tile, kv half
    const int q0 = b * M_ + mblk * 128 + w * 32;

    // anti-phase stagger for the second co-resident block (j+256)
    if (blk >= 256) {
        __builtin_amdgcn_s_sleep(49);           // ~3136 cyc ~ half a step
    }

    // Q fragments: B-operand; lane holds Q[q0+m][ch*16 + hl*8 ..+8]
    bf16x8 qf[16];
    #pragma unroll
    for (int ch = 0; ch < 16; ch++)
        qf[ch] = *reinterpret_cast<const bf16x8*>(
            Q + (size_t)(q0 + m) * 256 + ch * 16 + hl * 8);

    const f32x16 z16 = {0,0,0,0, 0,0,0,0, 0,0,0,0, 0,0,0,0};
    f32x16 acc[8];
    #pragma unroll
    for (int cb = 0; cb < 8; cb++) acc[cb] = z16;
    float lsum = 0.0f;                          // exp2 domain, fixed max = 0

    // staging sources: fully linear; per-thread base, +8192 ushorts/step
    const unsigned short* Ksrc =
        K3 + ((size_t)(b * 64 + h * 32) * 1024 + tid) * 8;
    const unsigned short* Vsrc =
        V3 + ((size_t)(b * 64 + h * 32) * 1024 + tid) * 8;

    auto stageK = [&](int step, int buf) {
        char* kb = smem + buf * 16384;
        const unsigned short* src = Ksrc + (size_t)step * 8192;
        #pragma unroll
        for (int it = 0; it < 4; it++)
            gload16(src + it * 2048, kb + (it * 256 + w * 64) * 16);
    };
    auto stageV = [&](int step, int buf) {
        char* vb = smem + 32768 + buf * 16384;
        const unsigned short* src = Vsrc + (size_t)step * 8192;
        #pragma unroll
        for (int it = 0; it < 4; it++)
            gload16(src + it * 2048, vb + (it * 256 + w * 64) * 16);
    };

    bf16x8 pf0, pf1;                            // P^T frags, carried across barrier
    auto qksm = [&](int s) {
        const char* kbl = smem + (s & 1) * 16384 + lane * 16;
        f32x16 sf = z16;
        __builtin_amdgcn_s_setprio(1);
        #pragma unroll
        for (int ch = 0; ch < 16; ch++) {
            bf16x8 kf = *reinterpret_cast<const bf16x8*>(kbl + ch * 1024);
            sf = __builtin_amdgcn_mfma_f32_32x32x16_bf16(kf, qf[ch], sf, 0, 0, 0);
        }
        __builtin_amdgcn_s_setprio(0);
        #pragma unroll
        for (int i = 0; i < 16; i++) {          // fixed-max: P = exp2(sf)
            sf[i] = exp2f(sf[i]);
            lsum += sf[i];
        }
        uint32_t pk0 = pkbf(sf[0], sf[1]),   pk1 = pkbf(sf[2], sf[3]);
        uint32_t pk2 = pkbf(sf[4], sf[5]),   pk3 = pkbf(sf[6], sf[7]);
        uint32_t pk4 = pkbf(sf[8], sf[9]),   pk5 = pkbf(sf[10], sf[11]);
        uint32_t pk6 = pkbf(sf[12], sf[13]), pk7 = pkbf(sf[14], sf[15]);
        uint2v r0 = __builtin_amdgcn_permlane32_swap(pk0, pk2, false, false);
        uint2v r1 = __builtin_amdgcn_permlane32_swap(pk1, pk3, false, false);
        uint2v r2 = __builtin_amdgcn_permlane32_swap(pk4, pk6, false, false);
        uint2v r3 = __builtin_amdgcn_permlane32_swap(pk5, pk7, false, false);
        uint4 u0; u0.x = r0[0]; u0.y = r1[0]; u0.z = r0[1]; u0.w = r1[1];
        uint4 u1; u1.x = r2[0]; u1.y = r3[0]; u1.z = r2[1]; u1.w = r3[1];
        pf0 = __builtin_bit_cast(bf16x8, u0);   // P^T[kv 0..15][q]
        pf1 = __builtin_bit_cast(bf16x8, u1);   // P^T[kv 16..31][q]
    };

    stageK(0, 0); stageV(0, 0);
    publish_barrier();                          // K0,V0 ready
    stageK(1, 1); stageV(1, 1);
    qksm(0);                                    // QK(0)+SM(0) reads K0

    int vcur = 0;                               // V buffer of step s
    for (int s = 0; s < 32; s++) {
        publish_barrier();                      // publishes stage(s+1)
        if (s + 2 < 32) {
            int vst = vcur + 2; if (vst >= 3) vst -= 3;
            stageK(s + 2, s & 1);               // K[s&1]: QK(s) done pre-barrier
            stageV(s + 2, vst);                 // V[(s+2)%3]: PV(s-1) done pre-barrier
        }
        // ---- PV(s) reads V[s%3]; QK(s+1) interleaves on the MFMA pipe
        const char* vbl = smem + 32768 + vcur * 16384 + lane * 16;
        bf16x8 p0 = pf0, p1 = pf1;
        __builtin_amdgcn_s_setprio(1);
        #pragma unroll
        for (int cb = 0; cb < 8; cb++) {
            bf16x8 v0 = *reinterpret_cast<const bf16x8*>(vbl + (cb * 2 + 0) * 1024);
            acc[cb] = __builtin_amdgcn_mfma_f32_32x32x16_bf16(v0, p0, acc[cb], 0, 0, 0);
            bf16x8 v1 = *reinterpret_cast<const bf16x8*>(vbl + (cb * 2 + 1) * 1024);
            acc[cb] = __builtin_amdgcn_mfma_f32_32x32x16_bf16(v1, p1, acc[cb], 0, 0, 0);
        }
        __builtin_amdgcn_s_setprio(0);
        if (s + 1 < 32) qksm(s + 1);            // reads K[(s+1)&1] (just published)
        vcur++; if (vcur >= 3) vcur -= 3;
    }

    // ---- epilogue: per-q-row lsum, write normalized bf16 partial + weight
    lsum += __shfl_xor(lsum, 32);
    float inv = 1.0f / lsum;
    size_t qrow = (size_t)(q0 + m);
    if (h0bf16 || h == 1) {
        unsigned short* myp = h ? part1 : part0;
        #pragma unroll
        for (int cb = 0; cb < 8; cb++)
            #pragma unroll
            for (int q4 = 0; q4 < 4; q4++) {
                int c0i = cb * 32 + q4 * 8 + 4 * hl;
                uint2 u;
                u.x = pkbf(acc[cb][q4 * 4 + 0] * inv, acc[cb][q4 * 4 + 1] * inv);
                u.y = pkbf(acc[cb][q4 * 4 + 2] * inv, acc[cb][q4 * 4 + 3] * inv);
                *reinterpret_cast<uint2*>(myp + qrow * 256 + c0i) = u;
            }
    } else {
        #pragma unroll
        for (int cb = 0; cb < 8; cb++)
            #pragma unroll
            for (int q4 = 0; q4 < 4; q4++) {
                int c0i = cb * 32 + q4 * 8 + 4 * hl;
                float4 o;
                o.x = acc[cb][q4 * 4 + 0] * inv;
                o.y = acc[cb][q4 * 4 + 1] * inv;
                o.z = acc[cb][q4 * 4 + 2] * inv;
                o.w = acc[cb][q4 * 4 + 3] * inv;
                *reinterpret_cast<float4*>(out + qrow * 256 + c0i) = o;
            }
    }
    if (hl == 0) ml[h * BM_ + qrow] = lsum;
}

// ---------------------------------------------------------------- kernel 4
// Merge halves (exact weighted combine) + LayerNorm + LeakyReLU.
// XCD-pinned: block reads the partials its own XCD's flash blocks wrote.
__global__ void merge_ln_kernel(const unsigned short* __restrict__ part0,
                                const unsigned short* __restrict__ part1,
                                const float* __restrict__ ml,
                                const float* __restrict__ gam,
                                const float* __restrict__ bet,
                                float* __restrict__ out,
                                int h0bf16) {
    int w = threadIdx.x >> 6, lane = threadIdx.x & 63;
    int blk = blockIdx.x;                       // 8192
    int xcd = blk & 7, j = blk >> 3;            // j: 0..1023
    int b = 2 * xcd + (j >> 9);
    size_t row = (size_t)b * 2048 + (size_t)(j & 511) * 4 + w;
    float w0 = ml[row], w1 = ml[BM_ + row];
    float rs = 1.0f / (w0 + w1);
    float a0 = w0 * rs, a1 = w1 * rs;
    float4 v;
    ushort4 p1 = *reinterpret_cast<const ushort4*>(part1 + row * 256 + lane * 4);
    if (h0bf16) {
        ushort4 p0 = *reinterpret_cast<const ushort4*>(part0 + row * 256 + lane * 4);
        v.x = a0 * bf2f(p0.x) + a1 * bf2f(p1.x);
        v.y = a0 * bf2f(p0.y) + a1 * bf2f(p1.y);
        v.z = a0 * bf2f(p0.z) + a1 * bf2f(p1.z);
        v.w = a0 * bf2f(p0.w) + a1 * bf2f(p1.w);
    } else {
        float4 o0 = *reinterpret_cast<float4*>(out + row * 256 + lane * 4);
        v.x = a0 * o0.x + a1 * bf2f(p1.x);
        v.y = a0 * o0.y + a1 * bf2f(p1.y);
        v.z = a0 * o0.z + a1 * bf2f(p1.z);
        v.w = a0 * o0.w + a1 * bf2f(p1.w);
    }
    float s = v.x + v.y + v.z + v.w;
    float q = v.x * v.x + v.y * v.y + v.z * v.z + v.w * v.w;
    #pragma unroll
    for (int m = 1; m < 64; m <<= 1) { s += __shfl_xor(s, m); q += __shfl_xor(q, m); }
    float mu = s * (1.0f / 256.0f);
    float var = q * (1.0f / 256.0f) - mu * mu;
    float rstd = rsqrtf(var + 1e-5f);
    float4 gg = *reinterpret_cast<const float4*>(gam + lane * 4);
    float4 bb = *reinterpret_cast<const float4*>(bet + lane * 4);
    float4 o;
    o.x = (v.x - mu) * rstd * gg.x + bb.x;
    o.y = (v.y - mu) * rstd * gg.y + bb.y;
    o.z = (v.z - mu) * rstd * gg.z + bb.z;
    o.w = (v.w - mu) * rstd * gg.w + bb.w;
    o.x = o.x >= 0.f ? o.x : 0.01f * o.x;
    o.y = o.y >= 0.f ? o.y : 0.01f * o.y;
    o.z = o.z >= 0.f ? o.z : 0.01f * o.z;
    o.w = o.w >= 0.f ? o.w : 0.01f * o.w;
    *reinterpret_cast<float4*>(out + row * 256 + lane * 4) = o;
}

// ---------------------------------------------------------------- launcher
extern "C" void kernel_launch(void* const* d_in, const int* in_sizes, int n_in,
                              void* d_out, int out_size, void* d_ws, size_t ws_size,
                              hipStream_t stream) {
    const float* local_feat = (const float*)d_in[0];
    const float* adj_w    = (const float*)d_in[3];
    const float* affine_w = (const float*)d_in[4];
    const float* affine_b = (const float*)d_in[5];
    const float* ln_g     = (const float*)d_in[6];
    const float* ln_b     = (const float*)d_in[7];
    float* out = (float*)d_out;

    char* ws = (char*)d_ws;
    unsigned short* nf    = (unsigned short*)(ws);                 // 16 MiB (dead after dual_gemm)
    unsigned short* q     = (unsigned short*)(ws + 16777216);      // 16 MiB
    unsigned short* v3    = (unsigned short*)(ws + 33554432);      // 16 MiB
    unsigned short* k3    = (unsigned short*)(ws + 50331648);      // 16 MiB -> 67108864
    unsigned short* part0 = (unsigned short*)(ws);                 // aliases nf (dead)
    unsigned short* part1;
    unsigned short* adjT5;
    unsigned short* affw;
    float*          norms;
    float*          ml;

    // primary layout high-water = 84,279,296 B (r12 proved >= 84,283,392 B)
    const size_t need = 84279296ull;
    int h0bf16 = (ws_size >= need) ? 1 : 0;
    if (h0bf16) {
        part1 = (unsigned short*)(ws + 67108864);  // 16 MiB -> 83886080
        adjT5 = (unsigned short*)(ws + 83886080);  // 128 KiB
        affw  = (unsigned short*)(ws + 84017152);  // 128 KiB
        norms = (float*)         (ws + 84148224);  // 128 KiB -> 84279296
        ml    = (float*)         (ws + 83886080);  // aliases adjT5+affw (dead)
    } else {
        part1 = (unsigned short*)(ws);             // aliases nf (part0 unused)
        adjT5 = (unsigned short*)(ws + 67108864);  // 128 KiB
        affw  = (unsigned short*)(ws + 67239936);  // 128 KiB
        norms = (float*)         (ws + 67371008);  // 128 KiB -> 67502080 (r9-proven)
        ml    = (float*)         (ws + 67108864);  // aliases adjT5+affw (dead)
    }

    l2norm_prep_kernel<<<8448, 256, 0, stream>>>(local_feat, nf, norms,
                                                 adj_w, affine_w, adjT5, affw);
    dual_gemm<<<BM_ / 128, 512, 0, stream>>>(nf, adjT5, affw, norms, affine_b, q, v3, k3);
    flash_kernel<<<512, 256, 0, stream>>>(q, k3, v3, out, part0, part1, ml, h0bf16);
    merge_ln_kernel<<<8192, 256, 0, stream>>>(part0, part1, ml, ln_g, ln_b, out, h0bf16);
}

// Round 17
// 122.241 us; speedup vs baseline: 2.7884x; 1.0131x over previous
//
#include <hip/hip_runtime.h>
#include <hip/hip_bf16.h>
#include <stdint.h>

// Shapes (fixed by the problem)
#define B_  16
#define M_  2048            // T*N
#define C_  256
#define BM_ 32768           // B_*M_

typedef __bf16 bf16x8 __attribute__((ext_vector_type(8)));
typedef __bf16 bf16x2 __attribute__((ext_vector_type(2)));
typedef float  f32x4  __attribute__((ext_vector_type(4)));
typedef float  f32x16 __attribute__((ext_vector_type(16)));
typedef unsigned int uint2v __attribute__((ext_vector_type(2)));

__device__ __forceinline__ unsigned short f2bf(float f) {
    uint32_t u = __builtin_bit_cast(uint32_t, f);
    u += 0x7fffu + ((u >> 16) & 1u);          // RNE
    return (unsigned short)(u >> 16);
}

__device__ __forceinline__ uint32_t pkbf(float a, float b) {
    bf16x2 t; t[0] = (__bf16)a; t[1] = (__bf16)b;   // compiler -> v_cvt_pk_bf16_f32
    return __builtin_bit_cast(uint32_t, t);
}

__device__ __forceinline__ float bf2f(unsigned short u) {
    return __builtin_bit_cast(float, ((uint32_t)u) << 16);
}

// async global->LDS, 16B/lane; LDS dest = wave-uniform base, HW adds lane*16
__device__ __forceinline__ void gload16(const void* g, void* l) {
    __builtin_amdgcn_global_load_lds(
        (const __attribute__((address_space(1))) void*)g,
        (__attribute__((address_space(3))) void*)l, 16, 0, 0);
}

// Explicit LDS-DMA publish: drain vmcnt BEFORE the barrier, fence scheduler.
__device__ __forceinline__ void publish_barrier() {
    asm volatile("s_waitcnt vmcnt(0)" ::: "memory");
    __builtin_amdgcn_sched_barrier(0);
    __syncthreads();
    __builtin_amdgcn_sched_barrier(0);
}

// ---------------------------------------------------------------- kernel 1
// FUSED: blocks 0..8191 = l2norm; blocks 8192..8447 = weight prep.
__global__ void l2norm_prep_kernel(const float* __restrict__ x,
                                   unsigned short* __restrict__ nf,
                                   float* __restrict__ norms,
                                   const float* __restrict__ adj,
                                   const float* __restrict__ affw,
                                   unsigned short* __restrict__ adjT5,
                                   unsigned short* __restrict__ affwB) {
    if (blockIdx.x >= 8192) {                   // prep part
        int idx = (blockIdx.x - 8192) * 256 + threadIdx.x;
        int d = idx >> 8, c = idx & 255;
        adjT5[d * 256 + c] = f2bf(7.2134752f * adj[c * 256 + d]);
        affwB[idx] = f2bf(affw[idx]);
        return;
    }
    int w = threadIdx.x >> 6, lane = threadIdx.x & 63;
    int row = blockIdx.x * 4 + w;
    const float4 v = *reinterpret_cast<const float4*>(x + (size_t)row * 256 + lane * 4);
    float ss = v.x * v.x + v.y * v.y + v.z * v.z + v.w * v.w;
    #pragma unroll
    for (int m = 1; m < 64; m <<= 1) ss += __shfl_xor(ss, m);
    float nrm = sqrtf(ss);
    float s = 1.0f / fmaxf(nrm, 1e-12f);
    ushort4 o;
    o.x = f2bf(v.x * s); o.y = f2bf(v.y * s); o.z = f2bf(v.z * s); o.w = f2bf(v.w * s);
    *reinterpret_cast<ushort4*>(nf + (size_t)row * 256 + lane * 4) = o;
    if (lane == 0) norms[row] = nrm;
}

// ---------------------------------------------------------------- kernel 2
// One pass over nf producing Q (row-major), V3 (flash-staging-linear),
// K3 (flash-staging-linear) — r9 version verbatim.
__global__ __launch_bounds__(512, 2)
void dual_gemm(const unsigned short* __restrict__ A,
               const unsigned short* __restrict__ B1,
               const unsigned short* __restrict__ B2,
               const float* __restrict__ norms,
               const float* __restrict__ bias,
               unsigned short* __restrict__ outQ,
               unsigned short* __restrict__ outV3,
               unsigned short* __restrict__ outK3) {
    __shared__ unsigned short bb1[256 * 56];
    __shared__ unsigned short bb2[256 * 56];
    int tid = threadIdx.x;
    int w = tid >> 6, lane = tid & 63, g = lane >> 4, r = lane & 15;
    int m0 = blockIdx.x * 128;

    const f32x4 z = {0.f, 0.f, 0.f, 0.f};
    f32x4 accq[16], accv[16];
    #pragma unroll
    for (int i = 0; i < 16; i++) { accq[i] = z; accv[i] = z; }

    int row = m0 + w * 16 + r;
    int kvblk_r = row >> 5, mrow = row & 31;

    for (int dc = 0; dc < 8; dc++) {
        __syncthreads();
        #pragma unroll
        for (int it = 0; it < 2; it++) {
            int n = (w * 2 + it) * 16 + (lane >> 2);
            int t = lane & 3;
            *reinterpret_cast<uint4*>(&bb1[n * 56 + t * 8]) =
                *reinterpret_cast<const uint4*>(B1 + (size_t)n * 256 + dc * 32 + t * 8);
            *reinterpret_cast<uint4*>(&bb2[n * 56 + t * 8]) =
                *reinterpret_cast<const uint4*>(B2 + (size_t)n * 256 + dc * 32 + t * 8);
        }
        __syncthreads();
        bf16x8 af = *reinterpret_cast<const bf16x8*>(
            A + (size_t)row * 256 + dc * 32 + g * 8);
        // K3 store: c-range = dc*32+g*8 -> ch = dc*2+(g>>1), khl = g&1
        {
            int ch = dc * 2 + (g >> 1);
            int khl = g & 1;
            *reinterpret_cast<bf16x8*>(
                outK3 + (size_t)kvblk_r * 8192 + ch * 512 + (khl * 32 + mrow) * 8) = af;
        }
        #pragma unroll
        for (int nf16 = 0; nf16 < 16; nf16++) {
            bf16x8 b1f = *reinterpret_cast<const bf16x8*>(&bb1[(nf16 * 16 + r) * 56 + g * 8]);
            accq[nf16] = __builtin_amdgcn_mfma_f32_16x16x32_bf16(af, b1f, accq[nf16], 0, 0, 0);
            bf16x8 b2f = *reinterpret_cast<const bf16x8*>(&bb2[(nf16 * 16 + r) * 56 + g * 8]);
            accv[nf16] = __builtin_amdgcn_mfma_f32_16x16x32_bf16(af, b2f, accv[nf16], 0, 0, 0);
        }
    }
    // Q epilogue: row-major
    #pragma unroll
    for (int nf16 = 0; nf16 < 16; nf16++) {
        int n = nf16 * 16 + r;
        #pragma unroll
        for (int j = 0; j < 4; j++) {
            int m = m0 + w * 16 + g * 4 + j;
            outQ[(size_t)m * 256 + n] = f2bf(accq[nf16][j]);
        }
    }
    // V3 epilogue: staging-linear layout, * norms + bias
    int mm = m0 + w * 16 + g * 4;               // kv row of acc elem 0 (4-aligned)
    int kvblk = mm >> 5;
    int kv0 = mm & 31;
    int jj  = kv0 >> 4;                         // 16-kv half
    int hl2 = (kv0 >> 3) & 1;                   // 8-kv sub
    int e0  = kv0 & 7;                          // 0 or 4
    float4 nr = *reinterpret_cast<const float4*>(norms + mm);
    #pragma unroll
    for (int nf16 = 0; nf16 < 16; nf16++) {
        int n = nf16 * 16 + r;
        int cb = n >> 5, mr2 = n & 31;
        int slot = (cb * 2 + jj) * 64 + hl2 * 32 + mr2;
        float bv = bias[n];
        ushort4 o;
        o.x = f2bf(accv[nf16][0] * nr.x + bv);
        o.y = f2bf(accv[nf16][1] * nr.y + bv);
        o.z = f2bf(accv[nf16][2] * nr.z + bv);
        o.w = f2bf(accv[nf16][3] * nr.w + bv);
        *reinterpret_cast<ushort4*>(outV3 + (size_t)kvblk * 8192 + slot * 8 + e0) = o;
    }
}

// ---------------------------------------------------------------- kernel 3
// Flash v17 = r15 skeleton + FUSED PV/QK INTERLEAVE: per iteration s the
// loop body strictly alternates  pv_mfma(i); qk_mfma(i);  (i = 0..15) so
// PV(s)'s 8 independent acc chains fill QK(s+1)'s serial-chain latency
// stalls at the instruction level (r15's two sequential loops never
// interleaved past the exp/pack block). Sync structure identical to r15.
// LDS 80KB: K0@0 K1@16K V0@32K V1@48K V2@64K; 2 blocks/CU = 160KB exactly.
__global__ __launch_bounds__(256, 2)
void flash_kernel(const unsigned short* __restrict__ Q,
                  const unsigned short* __restrict__ K3,
                  const unsigned short* __restrict__ V3,
                  float* __restrict__ out,
                  unsigned short* __restrict__ part0,
                  unsigned short* __restrict__ part1,
                  float* __restrict__ ml,
                  int h0bf16) {
    __shared__ __align__(16) char smem[81920];
    const int tid = threadIdx.x;
    const int w = tid >> 6, lane = tid & 63;
    const int hl = lane >> 5, m = lane & 31;    // lane half, lane-in-half
    const int blk = blockIdx.x;
    const int idx = blk >> 3;                   // 0..63
    const int b = (blk & 7) * 2 + (idx >> 5);   // XCD-pinned batch
    const int sub = idx & 31;
    const int mblk = sub >> 1, h = sub & 1;     // q-tile, kv half
    const int q0 = b * M_ + mblk * 128 + w * 32;

    // Q fragments: B-operand; lane holds Q[q0+m][ch*16 + hl*8 ..+8]
    bf16x8 qf[16];
    #pragma unroll
    for (int ch = 0; ch < 16; ch++)
        qf[ch] = *reinterpret_cast<const bf16x8*>(
            Q + (size_t)(q0 + m) * 256 + ch * 16 + hl * 8);

    const f32x16 z16 = {0,0,0,0, 0,0,0,0, 0,0,0,0, 0,0,0,0};
    f32x16 acc[8];
    #pragma unroll
    for (int cb = 0; cb < 8; cb++) acc[cb] = z16;
    float lsum = 0.0f;                          // exp2 domain, fixed max = 0

    // staging sources: fully linear; per-thread base, +8192 ushorts/step
    const unsigned short* Ksrc =
        K3 + ((size_t)(b * 64 + h * 32) * 1024 + tid) * 8;
    const unsigned short* Vsrc =
        V3 + ((size_t)(b * 64 + h * 32) * 1024 + tid) * 8;

    auto stageK = [&](int step, int buf) {
        char* kb = smem + buf * 16384;
        const unsigned short* src = Ksrc + (size_t)step * 8192;
        #pragma unroll
        for (int it = 0; it < 4; it++)
            gload16(src + it * 2048, kb + (it * 256 + w * 64) * 16);
    };
    auto stageV = [&](int step, int buf) {
        char* vb = smem + 32768 + buf * 16384;
        const unsigned short* src = Vsrc + (size_t)step * 8192;
        #pragma unroll
        for (int it = 0; it < 4; it++)
            gload16(src + it * 2048, vb + (it * 256 + w * 64) * 16);
    };

    bf16x8 pf0, pf1;                            // P^T frags, carried across barrier
    // softmax+pack: sf -> pf0/pf1 (fixed max = 0, exp2 domain)
    auto smpack = [&](f32x16& sf) {
        #pragma unroll
        for (int i = 0; i < 16; i++) {
            sf[i] = exp2f(sf[i]);
            lsum += sf[i];
        }
        uint32_t pk0 = pkbf(sf[0], sf[1]),   pk1 = pkbf(sf[2], sf[3]);
        uint32_t pk2 = pkbf(sf[4], sf[5]),   pk3 = pkbf(sf[6], sf[7]);
        uint32_t pk4 = pkbf(sf[8], sf[9]),   pk5 = pkbf(sf[10], sf[11]);
        uint32_t pk6 = pkbf(sf[12], sf[13]), pk7 = pkbf(sf[14], sf[15]);
        uint2v r0 = __builtin_amdgcn_permlane32_swap(pk0, pk2, false, false);
        uint2v r1 = __builtin_amdgcn_permlane32_swap(pk1, pk3, false, false);
        uint2v r2 = __builtin_amdgcn_permlane32_swap(pk4, pk6, false, false);
        uint2v r3 = __builtin_amdgcn_permlane32_swap(pk5, pk7, false, false);
        uint4 u0; u0.x = r0[0]; u0.y = r1[0]; u0.z = r0[1]; u0.w = r1[1];
        uint4 u1; u1.x = r2[0]; u1.y = r3[0]; u1.z = r2[1]; u1.w = r3[1];
        pf0 = __builtin_bit_cast(bf16x8, u0);   // P^T[kv 0..15][q]
        pf1 = __builtin_bit_cast(bf16x8, u1);   // P^T[kv 16..31][q]
    };

    stageK(0, 0); stageV(0, 0);
    publish_barrier();                          // K0,V0 ready
    stageK(1, 1); stageV(1, 1);
    {                                           // QK(0)+SM(0) reads K0
        const char* kbl = smem + lane * 16;
        f32x16 sf = z16;
        __builtin_amdgcn_s_setprio(1);
        #pragma unroll
        for (int ch = 0; ch < 16; ch++) {
            bf16x8 kf = *reinterpret_cast<const bf16x8*>(kbl + ch * 1024);
            sf = __builtin_amdgcn_mfma_f32_32x32x16_bf16(kf, qf[ch], sf, 0, 0, 0);
        }
        __builtin_amdgcn_s_setprio(0);
        smpack(sf);
    }

    int vcur = 0;                               // V buffer of step s
    for (int s = 0; s < 32; s++) {
        publish_barrier();                      // publishes stage(s+1)
        if (s + 2 < 32) {
            int vst = vcur + 2; if (vst >= 3) vst -= 3;
            stageK(s + 2, s & 1);               // K[s&1]: QK(s) done pre-barrier
            stageV(s + 2, vst);                 // V[(s+2)%3]: PV(s-1) done pre-barrier
        }
        const char* vbl = smem + 32768 + vcur * 16384 + lane * 16;
        bf16x8 p0 = pf0, p1 = pf1;
        if (s + 1 < 32) {
            // ---- fused: PV(s) interleaved 1:1 with QK(s+1)
            const char* kbl = smem + ((s + 1) & 1) * 16384 + lane * 16;
            f32x16 sf = z16;
            __builtin_amdgcn_s_setprio(1);
            #pragma unroll
            for (int i = 0; i < 16; i++) {
                bf16x8 vf = *reinterpret_cast<const bf16x8*>(vbl + i * 1024);
                acc[i >> 1] = __builtin_amdgcn_mfma_f32_32x32x16_bf16(
                    vf, (i & 1) ? p1 : p0, acc[i >> 1], 0, 0, 0);
                bf16x8 kf = *reinterpret_cast<const bf16x8*>(kbl + i * 1024);
                sf = __builtin_amdgcn_mfma_f32_32x32x16_bf16(kf, qf[i], sf, 0, 0, 0);
            }
            __builtin_amdgcn_s_setprio(0);
            smpack(sf);                         // SM(s+1) -> pf0/pf1
        } else {
            // ---- tail: PV(31) only
            __builtin_amdgcn_s_setprio(1);
            #pragma unroll
            for (int i = 0; i < 16; i++) {
                bf16x8 vf = *reinterpret_cast<const bf16x8*>(vbl + i * 1024);
                acc[i >> 1] = __builtin_amdgcn_mfma_f32_32x32x16_bf16(
                    vf, (i & 1) ? p1 : p0, acc[i >> 1], 0, 0, 0);
            }
            __builtin_amdgcn_s_setprio(0);
        }
        vcur++; if (vcur >= 3) vcur -= 3;
    }

    // ---- epilogue: per-q-row lsum, write normalized bf16 partial + weight
    lsum += __shfl_xor(lsum, 32);
    float inv = 1.0f / lsum;
    size_t qrow = (size_t)(q0 + m);
    if (h0bf16 || h == 1) {
        unsigned short* myp = h ? part1 : part0;
        #pragma unroll
        for (int cb = 0; cb < 8; cb++)
            #pragma unroll
            for (int q4 = 0; q4 < 4; q4++) {
                int c0i = cb * 32 + q4 * 8 + 4 * hl;
                uint2 u;
                u.x = pkbf(acc[cb][q4 * 4 + 0] * inv, acc[cb][q4 * 4 + 1] * inv);
                u.y = pkbf(acc[cb][q4 * 4 + 2] * inv, acc[cb][q4 * 4 + 3] * inv);
                *reinterpret_cast<uint2*>(myp + qrow * 256 + c0i) = u;
            }
    } else {
        #pragma unroll
        for (int cb = 0; cb < 8; cb++)
            #pragma unroll
            for (int q4 = 0; q4 < 4; q4++) {
                int c0i = cb * 32 + q4 * 8 + 4 * hl;
                float4 o;
                o.x = acc[cb][q4 * 4 + 0] * inv;
                o.y = acc[cb][q4 * 4 + 1] * inv;
                o.z = acc[cb][q4 * 4 + 2] * inv;
                o.w = acc[cb][q4 * 4 + 3] * inv;
                *reinterpret_cast<float4*>(out + qrow * 256 + c0i) = o;
            }
    }
    if (hl == 0) ml[h * BM_ + qrow] = lsum;
}

// ---------------------------------------------------------------- kernel 4
// Merge halves (exact weighted combine) + LayerNorm + LeakyReLU.
// XCD-pinned: block reads the partials its own XCD's flash blocks wrote.
__global__ void merge_ln_kernel(const unsigned short* __restrict__ part0,
                                const unsigned short* __restrict__ part1,
                                const float* __restrict__ ml,
                                const float* __restrict__ gam,
                                const float* __restrict__ bet,
                                float* __restrict__ out,
                                int h0bf16) {
    int w = threadIdx.x >> 6, lane = threadIdx.x & 63;
    int blk = blockIdx.x;                       // 8192
    int xcd = blk & 7, j = blk >> 3;            // j: 0..1023
    int b = 2 * xcd + (j >> 9);
    size_t row = (size_t)b * 2048 + (size_t)(j & 511) * 4 + w;
    float w0 = ml[row], w1 = ml[BM_ + row];
    float rs = 1.0f / (w0 + w1);
    float a0 = w0 * rs, a1 = w1 * rs;
    float4 v;
    ushort4 p1 = *reinterpret_cast<const ushort4*>(part1 + row * 256 + lane * 4);
    if (h0bf16) {
        ushort4 p0 = *reinterpret_cast<const ushort4*>(part0 + row * 256 + lane * 4);
        v.x = a0 * bf2f(p0.x) + a1 * bf2f(p1.x);
        v.y = a0 * bf2f(p0.y) + a1 * bf2f(p1.y);
        v.z = a0 * bf2f(p0.z) + a1 * bf2f(p1.z);
        v.w = a0 * bf2f(p0.w) + a1 * bf2f(p1.w);
    } else {
        float4 o0 = *reinterpret_cast<float4*>(out + row * 256 + lane * 4);
        v.x = a0 * o0.x + a1 * bf2f(p1.x);
        v.y = a0 * o0.y + a1 * bf2f(p1.y);
        v.z = a0 * o0.z + a1 * bf2f(p1.z);
        v.w = a0 * o0.w + a1 * bf2f(p1.w);
    }
    float s = v.x + v.y + v.z + v.w;
    float q = v.x * v.x + v.y * v.y + v.z * v.z + v.w * v.w;
    #pragma unroll
    for (int m = 1; m < 64; m <<= 1) { s += __shfl_xor(s, m); q += __shfl_xor(q, m); }
    float mu = s * (1.0f / 256.0f);
    float var = q * (1.0f / 256.0f) - mu * mu;
    float rstd = rsqrtf(var + 1e-5f);
    float4 gg = *reinterpret_cast<const float4*>(gam + lane * 4);
    float4 bb = *reinterpret_cast<const float4*>(bet + lane * 4);
    float4 o;
    o.x = (v.x - mu) * rstd * gg.x + bb.x;
    o.y = (v.y - mu) * rstd * gg.y + bb.y;
    o.z = (v.z - mu) * rstd * gg.z + bb.z;
    o.w = (v.w - mu) * rstd * gg.w + bb.w;
    o.x = o.x >= 0.f ? o.x : 0.01f * o.x;
    o.y = o.y >= 0.f ? o.y : 0.01f * o.y;
    o.z = o.z >= 0.f ? o.z : 0.01f * o.z;
    o.w = o.w >= 0.f ? o.w : 0.01f * o.w;
    *reinterpret_cast<float4*>(out + row * 256 + lane * 4) = o;
}

// ---------------------------------------------------------------- launcher
extern "C" void kernel_launch(void* const* d_in, const int* in_sizes, int n_in,
                              void* d_out, int out_size, void* d_ws, size_t ws_size,
                              hipStream_t stream) {
    const float* local_feat = (const float*)d_in[0];
    const float* adj_w    = (const float*)d_in[3];
    const float* affine_w = (const float*)d_in[4];
    const float* affine_b = (const float*)d_in[5];
    const float* ln_g     = (const float*)d_in[6];
    const float* ln_b     = (const float*)d_in[7];
    float* out = (float*)d_out;

    char* ws = (char*)d_ws;
    unsigned short* nf    = (unsigned short*)(ws);                 // 16 MiB (dead after dual_gemm)
    unsigned short* q     = (unsigned short*)(ws + 16777216);      // 16 MiB
    unsigned short* v3    = (unsigned short*)(ws + 33554432);      // 16 MiB
    unsigned short* k3    = (unsigned short*)(ws + 50331648);      // 16 MiB -> 67108864
    unsigned short* part0 = (unsigned short*)(ws);                 // aliases nf (dead)
    unsigned short* part1;
    unsigned short* adjT5;
    unsigned short* affw;
    float*          norms;
    float*          ml;

    // primary layout high-water = 84,279,296 B (r12 proved >= 84,283,392 B)
    const size_t need = 84279296ull;
    int h0bf16 = (ws_size >= need) ? 1 : 0;
    if (h0bf16) {
        part1 = (unsigned short*)(ws + 67108864);  // 16 MiB -> 83886080
        adjT5 = (unsigned short*)(ws + 83886080);  // 128 KiB
        affw  = (unsigned short*)(ws + 84017152);  // 128 KiB
        norms = (float*)         (ws + 84148224);  // 128 KiB -> 84279296
        ml    = (float*)         (ws + 83886080);  // aliases adjT5+affw (dead)
    } else {
        part1 = (unsigned short*)(ws);             // aliases nf (part0 unused)
        adjT5 = (unsigned short*)(ws + 67108864);  // 128 KiB
        affw  = (unsigned short*)(ws + 67239936);  // 128 KiB
        norms = (float*)         (ws + 67371008);  // 128 KiB -> 67502080 (r9-proven)
        ml    = (float*)         (ws + 67108864);  // aliases adjT5+affw (dead)
    }

    l2norm_prep_kernel<<<8448, 256, 0, stream>>>(local_feat, nf, norms,
                                                 adj_w, affine_w, adjT5, affw);
    dual_gemm<<<BM_ / 128, 512, 0, stream>>>(nf, adjT5, affw, norms, affine_b, q, v3, k3);
    flash_kernel<<<512, 256, 0, stream>>>(q, k3, v3, out, part0, part1, ml, h0bf16);
    merge_ln_kernel<<<8192, 256, 0, stream>>>(part0, part1, ml, ln_g, ln_b, out, h0bf16);
}